// Round 1
// baseline (11447.379 us; speedup 1.0000x reference)
//
#include <hip/hip_runtime.h>
#include <stdint.h>

#define NN   100000
#define NE   1600000
#define IN_F 512
#define HID  256
#define OUTF 16

typedef unsigned int u32;

__device__ __forceinline__ u32 rotl32(u32 x, int r){ return (x<<r)|(x>>(32-r)); }

// JAX threefry2x32, key=(0,42), counts=(0,i) -- partitionable random_bits path.
// bits = x0 ^ x1; uniform<0.5  <=>  top bit of bits == 0.
__device__ __forceinline__ bool drop_keep(u32 i){
    const u32 ks0 = 0u, ks1 = 42u, ks2 = 0x1BD11BDAu ^ 0u ^ 42u;
    u32 x0 = 0u + ks0;
    u32 x1 = i  + ks1;
#define TFR(r) { x0 += x1; x1 = rotl32(x1,(r)); x1 ^= x0; }
    TFR(13) TFR(15) TFR(26) TFR(6)   x0 += ks1; x1 += ks2 + 1u;
    TFR(17) TFR(29) TFR(16) TFR(24)  x0 += ks2; x1 += ks0 + 2u;
    TFR(13) TFR(15) TFR(26) TFR(6)   x0 += ks0; x1 += ks1 + 3u;
    TFR(17) TFR(29) TFR(16) TFR(24)  x0 += ks1; x1 += ks2 + 4u;
    TFR(13) TFR(15) TFR(26) TFR(6)   x0 += ks2; x1 += ks0 + 5u;
#undef TFR
    return ((x0 ^ x1) >> 31) == 0u;
}

__global__ __launch_bounds__(256) void degree_kernel(const int* __restrict__ src,
                                                     const int* __restrict__ dst,
                                                     float* dego, float* degi){
    int i = blockIdx.x * blockDim.x + threadIdx.x;
    if (i < NE) {
        atomicAdd(&dego[src[i]], 1.0f);
        atomicAdd(&degi[dst[i]], 1.0f);
    }
}

__global__ __launch_bounds__(256) void finalize_deg(float* dego, float* degi){
    int i = blockIdx.x * blockDim.x + threadIdx.x;
    if (i < NN) {
        dego[i] = rsqrtf(fmaxf(dego[i], 1.0f));
        degi[i] = rsqrtf(fmaxf(degi[i], 1.0f));
    }
}

// C[m][0..255] = (A[m][:] * scale[m]) @ B,  A: NN x K row-major, B: K x 256 row-major
template<int K>
__global__ __launch_bounds__(256) void gemm_scaled(const float* __restrict__ A,
                                                   const float* __restrict__ scale,
                                                   const float* __restrict__ B,
                                                   float* __restrict__ C){
    const int BM = 64, BN = 64, BK = 16;
    __shared__ float As[BK][BM];   // transposed A tile
    __shared__ float Bs[BK][BN];
    const int bm = blockIdx.x * BM;
    const int bn = blockIdx.y * BN;
    const int t  = threadIdx.x;

    const int ar  = t >> 2;            // 0..63 A-tile row
    const int akq = (t & 3) * 4;       // k offset within tile (float4)
    const int bk  = t >> 4;            // 0..15 B-tile k
    const int bnq = (t & 15) * 4;      // n offset (float4)
    const int ty  = t >> 4, tx = t & 15;

    const int arow = bm + ar;
    const bool aval = (arow < NN);
    const float s = aval ? scale[arow] : 0.0f;
    const float* Aptr = A + (size_t)(aval ? arow : 0) * K;

    float acc[4][4] = {};

    for (int k0 = 0; k0 < K; k0 += BK) {
        float4 av = make_float4(0.f,0.f,0.f,0.f);
        if (aval) av = *(const float4*)(Aptr + k0 + akq);
        As[akq+0][ar] = av.x * s;
        As[akq+1][ar] = av.y * s;
        As[akq+2][ar] = av.z * s;
        As[akq+3][ar] = av.w * s;
        float4 bv = *(const float4*)(B + (size_t)(k0 + bk) * HID + bn + bnq);
        *(float4*)&Bs[bk][bnq] = bv;
        __syncthreads();
        #pragma unroll
        for (int kk = 0; kk < BK; ++kk) {
            float4 a4 = *(const float4*)&As[kk][ty*4];
            float4 b4 = *(const float4*)&Bs[kk][tx*4];
            float a[4] = {a4.x, a4.y, a4.z, a4.w};
            float b[4] = {b4.x, b4.y, b4.z, b4.w};
            #pragma unroll
            for (int i = 0; i < 4; ++i)
                #pragma unroll
                for (int j = 0; j < 4; ++j)
                    acc[i][j] += a[i] * b[j];
        }
        __syncthreads();
    }

    #pragma unroll
    for (int i = 0; i < 4; ++i) {
        int m = bm + ty*4 + i;
        if (m < NN) {
            float4 v = make_float4(acc[i][0], acc[i][1], acc[i][2], acc[i][3]);
            *(float4*)(C + (size_t)m * HID + bn + tx*4) = v;
        }
    }
}

// one 64-lane wave per edge; lane handles 4 floats of the 256-wide row
__global__ __launch_bounds__(256) void scatter_add(const float* __restrict__ H,
                                                   const int* __restrict__ src,
                                                   const int* __restrict__ dst,
                                                   float* __restrict__ AGG){
    int wave = (int)((blockIdx.x * (size_t)blockDim.x + threadIdx.x) >> 6);
    int lane = threadIdx.x & 63;
    if (wave >= NE) return;
    int s = src[wave], d = dst[wave];
    const float4 v = *(const float4*)(H + (size_t)s * HID + lane * 4);
    float* dp = AGG + (size_t)d * HID + lane * 4;
    atomicAdd(dp + 0, v.x);
    atomicAdd(dp + 1, v.y);
    atomicAdd(dp + 2, v.z);
    atomicAdd(dp + 3, v.w);
}

// h1 = relu(agg*isdi + b1); dropout (threefry); output WITHOUT isdo (GEMM2 applies it)
__global__ __launch_bounds__(256) void relu_drop(const float* __restrict__ AGG,
                                                 const float* __restrict__ isdi,
                                                 const float* __restrict__ b1,
                                                 float* __restrict__ Hout){
    int idx = blockIdx.x * blockDim.x + threadIdx.x;
    if (idx >= NN * HID) return;
    int n = idx >> 8;
    int j = idx & 255;
    float h = AGG[idx] * isdi[n] + b1[j];
    h = fmaxf(h, 0.0f);
    h = drop_keep((u32)idx) ? h * 2.0f : 0.0f;
    Hout[idx] = h;
}

// out[n][k] = sum_j (AGG[n][j]*isdi[n] + b2[j]) * W3[j][k] + b3[k]
__global__ __launch_bounds__(256) void head_kernel(const float* __restrict__ AGG,
                                                   const float* __restrict__ isdi,
                                                   const float* __restrict__ b2,
                                                   const float* __restrict__ W3,
                                                   const float* __restrict__ b3,
                                                   float* __restrict__ out){
    __shared__ float W3s[HID * OUTF];
    __shared__ float b2s[HID];
    int t = threadIdx.x;
    for (int i = t; i < HID * OUTF; i += 256) W3s[i] = W3[i];
    for (int i = t; i < HID; i += 256) b2s[i] = b2[i];
    __syncthreads();
    int nl = t >> 4, k = t & 15;
    int n = blockIdx.x * 16 + nl;
    if (n >= NN) return;
    float sd = isdi[n];
    const float* row = AGG + (size_t)n * HID;
    float acc = 0.0f;
    for (int j = 0; j < HID; ++j) {
        float h = row[j] * sd + b2s[j];
        acc += h * W3s[j * OUTF + k];
    }
    out[(size_t)n * OUTF + k] = acc + b3[k];
}

extern "C" void kernel_launch(void* const* d_in, const int* in_sizes, int n_in,
                              void* d_out, int out_size, void* d_ws, size_t ws_size,
                              hipStream_t stream) {
    const float* features = (const float*)d_in[0];
    const int*   src      = (const int*)  d_in[1];
    const int*   dst      = (const int*)  d_in[2];
    const float* W1       = (const float*)d_in[3];
    const float* b1       = (const float*)d_in[4];
    const float* W2       = (const float*)d_in[5];
    const float* b2       = (const float*)d_in[6];
    const float* W3       = (const float*)d_in[7];
    const float* b3       = (const float*)d_in[8];
    float* out = (float*)d_out;

    // workspace layout
    char* ws = (char*)d_ws;
    float* isdo = (float*)ws;                       // NN floats (deg_out -> rsqrt)
    float* isdi = (float*)(ws + (size_t)NN * 4);    // NN floats
    const size_t BUF = (size_t)NN * HID * 4;        // 102.4 MB
    float* bufA = (float*)(ws + (1u << 20));
    float* bufB = (float*)(ws + (1u << 20) + BUF);
    if (ws_size < (1u << 20) + 2 * BUF) return;     // insufficient scratch; fail loudly

    // degrees
    hipMemsetAsync(isdo, 0, (size_t)NN * 4 * 2, stream);
    degree_kernel<<<(NE + 255) / 256, 256, 0, stream>>>(src, dst, isdo, isdi);
    finalize_deg<<<(NN + 255) / 256, 256, 0, stream>>>(isdo, isdi);

    dim3 ggrid((NN + 63) / 64, HID / 64);

    // layer 1
    gemm_scaled<IN_F><<<ggrid, 256, 0, stream>>>(features, isdo, W1, bufA);   // h0
    hipMemsetAsync(bufB, 0, BUF, stream);
    scatter_add<<<NE / 4, 256, 0, stream>>>(bufA, src, dst, bufB);            // agg1
    relu_drop<<<(NN * HID + 255) / 256, 256, 0, stream>>>(bufB, isdi, b1, bufA); // h1 (dropped)

    // layer 2
    gemm_scaled<HID><<<ggrid, 256, 0, stream>>>(bufA, isdo, W2, bufB);        // h2pre
    hipMemsetAsync(bufA, 0, BUF, stream);
    scatter_add<<<NE / 4, 256, 0, stream>>>(bufB, src, dst, bufA);            // agg2

    // head
    head_kernel<<<(NN + 15) / 16, 256, 0, stream>>>(bufA, isdi, b2, W3, b3, out);
}

// Round 2
// 1465.051 us; speedup vs baseline: 7.8136x; 7.8136x over previous
//
#include <hip/hip_runtime.h>
#include <stdint.h>

#define NN   100000
#define NE   1600000
#define IN_F 512
#define HID  256
#define OUTF 16

typedef unsigned int u32;

__device__ __forceinline__ u32 rotl32(u32 x, int r){ return (x<<r)|(x>>(32-r)); }

// JAX threefry2x32, key=(0,42), counts=(0,i). keep <=> top bit of (x0^x1)==0.
__device__ __forceinline__ bool drop_keep(u32 i){
    const u32 ks0 = 0u, ks1 = 42u, ks2 = 0x1BD11BDAu ^ 0u ^ 42u;
    u32 x0 = 0u + ks0;
    u32 x1 = i  + ks1;
#define TFR(r) { x0 += x1; x1 = rotl32(x1,(r)); x1 ^= x0; }
    TFR(13) TFR(15) TFR(26) TFR(6)   x0 += ks1; x1 += ks2 + 1u;
    TFR(17) TFR(29) TFR(16) TFR(24)  x0 += ks2; x1 += ks0 + 2u;
    TFR(13) TFR(15) TFR(26) TFR(6)   x0 += ks0; x1 += ks1 + 3u;
    TFR(17) TFR(29) TFR(16) TFR(24)  x0 += ks1; x1 += ks2 + 4u;
    TFR(13) TFR(15) TFR(26) TFR(6)   x0 += ks2; x1 += ks0 + 5u;
#undef TFR
    return ((x0 ^ x1) >> 31) == 0u;
}

// ---------------- CSR build ----------------

__global__ __launch_bounds__(256) void hist_kernel(const int* __restrict__ src,
                                                   const int* __restrict__ dst,
                                                   int* deg_out, int* deg_in){
    int i = blockIdx.x * blockDim.x + threadIdx.x;
    if (i < NE) {
        atomicAdd(&deg_out[src[i]], 1);
        atomicAdd(&deg_in[dst[i]], 1);
    }
}

__global__ __launch_bounds__(256) void finalize_deg(const int* deg_out, const int* deg_in,
                                                    float* isdo, float* isdi){
    int i = blockIdx.x * blockDim.x + threadIdx.x;
    if (i < NN) {
        isdo[i] = rsqrtf(fmaxf((float)deg_out[i], 1.0f));
        isdi[i] = rsqrtf(fmaxf((float)deg_in[i], 1.0f));
    }
}

// single-block exclusive scan of deg_in[NN] -> row_ptr[NN+1]
__global__ __launch_bounds__(1024) void scan_kernel(const int* __restrict__ deg,
                                                    int* __restrict__ row_ptr){
    __shared__ int sh[1024];
    __shared__ int carry;
    int t = threadIdx.x;
    if (t == 0) carry = 0;
    __syncthreads();
    for (int base = 0; base < NN; base += 1024) {
        int i = base + t;
        int v = (i < NN) ? deg[i] : 0;
        sh[t] = v;
        __syncthreads();
        for (int off = 1; off < 1024; off <<= 1) {
            int add = (t >= off) ? sh[t - off] : 0;
            __syncthreads();
            sh[t] += add;
            __syncthreads();
        }
        int incl = sh[t];
        int c = carry;                // carry stable here (written after last sync)
        if (i < NN) row_ptr[i] = c + incl - v;
        __syncthreads();
        if (t == 0) carry = c + sh[1023];
        __syncthreads();
    }
    if (t == 0) row_ptr[NN] = carry;
}

__global__ __launch_bounds__(256) void copy_int(const int* __restrict__ a, int* __restrict__ b, int n){
    int i = blockIdx.x * blockDim.x + threadIdx.x;
    if (i < n) b[i] = a[i];
}

__global__ __launch_bounds__(256) void fill_csr(const int* __restrict__ src,
                                                const int* __restrict__ dst,
                                                int* cursor, int* __restrict__ col_src){
    int i = blockIdx.x * blockDim.x + threadIdx.x;
    if (i < NE) {
        int pos = atomicAdd(&cursor[dst[i]], 1);
        col_src[pos] = src[i];
    }
}

// ---------------- GEMM (fp32, isdo pre-scale fused) ----------------
// C[m][0..255] = (A[m][:] * scale[m]) @ B,  A: NN x K row-major, B: K x 256 row-major
template<int K>
__global__ __launch_bounds__(256) void gemm_scaled(const float* __restrict__ A,
                                                   const float* __restrict__ scale,
                                                   const float* __restrict__ B,
                                                   float* __restrict__ C){
    const int BM = 64, BN = 64, BK = 16;
    __shared__ float As[BK][BM];
    __shared__ float Bs[BK][BN];
    const int bm = blockIdx.x * BM;
    const int bn = blockIdx.y * BN;
    const int t  = threadIdx.x;

    const int ar  = t >> 2;
    const int akq = (t & 3) * 4;
    const int bk  = t >> 4;
    const int bnq = (t & 15) * 4;
    const int ty  = t >> 4, tx = t & 15;

    const int arow = bm + ar;
    const bool aval = (arow < NN);
    const float s = aval ? scale[arow] : 0.0f;
    const float* Aptr = A + (size_t)(aval ? arow : 0) * K;

    float acc[4][4] = {};

    for (int k0 = 0; k0 < K; k0 += BK) {
        float4 av = make_float4(0.f,0.f,0.f,0.f);
        if (aval) av = *(const float4*)(Aptr + k0 + akq);
        As[akq+0][ar] = av.x * s;
        As[akq+1][ar] = av.y * s;
        As[akq+2][ar] = av.z * s;
        As[akq+3][ar] = av.w * s;
        float4 bv = *(const float4*)(B + (size_t)(k0 + bk) * HID + bn + bnq);
        *(float4*)&Bs[bk][bnq] = bv;
        __syncthreads();
        #pragma unroll
        for (int kk = 0; kk < BK; ++kk) {
            float4 a4 = *(const float4*)&As[kk][ty*4];
            float4 b4 = *(const float4*)&Bs[kk][tx*4];
            float a[4] = {a4.x, a4.y, a4.z, a4.w};
            float b[4] = {b4.x, b4.y, b4.z, b4.w};
            #pragma unroll
            for (int i = 0; i < 4; ++i)
                #pragma unroll
                for (int j = 0; j < 4; ++j)
                    acc[i][j] += a[i] * b[j];
        }
        __syncthreads();
    }

    #pragma unroll
    for (int i = 0; i < 4; ++i) {
        int m = bm + ty*4 + i;
        if (m < NN) {
            float4 v = make_float4(acc[i][0], acc[i][1], acc[i][2], acc[i][3]);
            *(float4*)(C + (size_t)m * HID + bn + tx*4) = v;
        }
    }
}

// ---------------- gather aggregation ----------------
// one wave per node; lane handles 4 of 256 cols.
// out[n][:] = (sum_{e in in(n)} H[src_e][:]) * isdi[n] + bias ; optional relu+dropout
template<bool RELU_DROP>
__global__ __launch_bounds__(256) void gather_agg(const float* __restrict__ H,
                                                  const int* __restrict__ row_ptr,
                                                  const int* __restrict__ col_src,
                                                  const float* __restrict__ isdi,
                                                  const float* __restrict__ bias,
                                                  float* __restrict__ out){
    int node = blockIdx.x * 4 + (threadIdx.x >> 6);
    int lane = threadIdx.x & 63;
    if (node >= NN) return;
    int e   = row_ptr[node];
    int end = row_ptr[node + 1];

    float a0=0.f,a1=0.f,a2=0.f,a3=0.f;
    float c0=0.f,c1=0.f,c2=0.f,c3=0.f;
    const int off = lane * 4;

    for (; e + 4 <= end; e += 4) {
        int s0 = col_src[e], s1 = col_src[e+1], s2 = col_src[e+2], s3 = col_src[e+3];
        float4 v0 = *(const float4*)(H + (size_t)s0 * HID + off);
        float4 v1 = *(const float4*)(H + (size_t)s1 * HID + off);
        float4 v2 = *(const float4*)(H + (size_t)s2 * HID + off);
        float4 v3 = *(const float4*)(H + (size_t)s3 * HID + off);
        a0 += v0.x + v2.x; a1 += v0.y + v2.y; a2 += v0.z + v2.z; a3 += v0.w + v2.w;
        c0 += v1.x + v3.x; c1 += v1.y + v3.y; c2 += v1.z + v3.z; c3 += v1.w + v3.w;
    }
    for (; e < end; ++e) {
        int s0 = col_src[e];
        float4 v0 = *(const float4*)(H + (size_t)s0 * HID + off);
        a0 += v0.x; a1 += v0.y; a2 += v0.z; a3 += v0.w;
    }
    a0 += c0; a1 += c1; a2 += c2; a3 += c3;

    float sd = isdi[node];
    float4 b = *(const float4*)(bias + off);
    float h0 = a0 * sd + b.x;
    float h1 = a1 * sd + b.y;
    float h2 = a2 * sd + b.z;
    float h3 = a3 * sd + b.w;

    if (RELU_DROP) {
        u32 base = (u32)node * HID + off;
        h0 = (drop_keep(base+0) ? fmaxf(h0,0.f)*2.0f : 0.f);
        h1 = (drop_keep(base+1) ? fmaxf(h1,0.f)*2.0f : 0.f);
        h2 = (drop_keep(base+2) ? fmaxf(h2,0.f)*2.0f : 0.f);
        h3 = (drop_keep(base+3) ? fmaxf(h3,0.f)*2.0f : 0.f);
    }
    *(float4*)(out + (size_t)node * HID + off) = make_float4(h0,h1,h2,h3);
}

// ---------------- head: out[n][k] = sum_j H2[n][j]*W3[j][k] + b3[k] ----------------
__global__ __launch_bounds__(256) void head_kernel(const float* __restrict__ H2,
                                                   const float* __restrict__ W3,
                                                   const float* __restrict__ b3,
                                                   float* __restrict__ out){
    __shared__ float W3s[HID * OUTF];
    int t = threadIdx.x;
    for (int i = t; i < HID * OUTF; i += 256) W3s[i] = W3[i];
    __syncthreads();
    int nl = t >> 4, k = t & 15;
    int n = blockIdx.x * 16 + nl;
    if (n >= NN) return;
    const float* row = H2 + (size_t)n * HID;
    float acc = 0.0f;
    for (int j = 0; j < HID; ++j)
        acc += row[j] * W3s[j * OUTF + k];
    out[(size_t)n * OUTF + k] = acc + b3[k];
}

extern "C" void kernel_launch(void* const* d_in, const int* in_sizes, int n_in,
                              void* d_out, int out_size, void* d_ws, size_t ws_size,
                              hipStream_t stream) {
    const float* features = (const float*)d_in[0];
    const int*   src      = (const int*)  d_in[1];
    const int*   dst      = (const int*)  d_in[2];
    const float* W1       = (const float*)d_in[3];
    const float* b1       = (const float*)d_in[4];
    const float* W2       = (const float*)d_in[5];
    const float* b2       = (const float*)d_in[6];
    const float* W3       = (const float*)d_in[7];
    const float* b3       = (const float*)d_in[8];
    float* out = (float*)d_out;

    // workspace layout
    char* ws = (char*)d_ws;
    size_t o = 0;
    float* isdo    = (float*)(ws + o); o += (size_t)NN * 4;
    float* isdi    = (float*)(ws + o); o += (size_t)NN * 4;
    int*   deg_out = (int*)  (ws + o); o += (size_t)NN * 4;
    int*   deg_in  = (int*)  (ws + o); o += (size_t)NN * 4;
    int*   row_ptr = (int*)  (ws + o); o += (size_t)(NN + 1) * 4;
    int*   cursor  = (int*)  (ws + o); o += (size_t)NN * 4;
    int*   col_src = (int*)  (ws + o); o += (size_t)NE * 4;
    o = (o + 255) & ~(size_t)255;
    const size_t BUF = (size_t)NN * HID * 4;  // 102.4 MB
    float* bufA = (float*)(ws + o);
    float* bufB = (float*)(ws + o + BUF);
    if (ws_size < o + 2 * BUF) return;  // insufficient scratch

    // ---- CSR build + degree norms ----
    hipMemsetAsync(deg_out, 0, (size_t)NN * 4 * 2, stream);  // deg_out + deg_in
    hist_kernel<<<(NE + 255) / 256, 256, 0, stream>>>(src, dst, deg_out, deg_in);
    finalize_deg<<<(NN + 255) / 256, 256, 0, stream>>>(deg_out, deg_in, isdo, isdi);
    scan_kernel<<<1, 1024, 0, stream>>>(deg_in, row_ptr);
    copy_int<<<(NN + 255) / 256, 256, 0, stream>>>(row_ptr, cursor, NN);
    fill_csr<<<(NE + 255) / 256, 256, 0, stream>>>(src, dst, cursor, col_src);

    dim3 ggrid((NN + 63) / 64, HID / 64);
    const int agrid = (NN + 3) / 4;

    // ---- layer 1 ----
    gemm_scaled<IN_F><<<ggrid, 256, 0, stream>>>(features, isdo, W1, bufA);
    gather_agg<true><<<agrid, 256, 0, stream>>>(bufA, row_ptr, col_src, isdi, b1, bufB);

    // ---- layer 2 ----
    gemm_scaled<HID><<<ggrid, 256, 0, stream>>>(bufB, isdo, W2, bufA);
    gather_agg<false><<<agrid, 256, 0, stream>>>(bufA, row_ptr, col_src, isdi, b2, bufB);

    // ---- head ----
    head_kernel<<<(NN + 15) / 16, 256, 0, stream>>>(bufB, W3, b3, out);
}

// Round 3
// 695.023 us; speedup vs baseline: 16.4705x; 2.1079x over previous
//
#include <hip/hip_runtime.h>
#include <stdint.h>

#define NN    100000
#define NE    1600000
#define IN_F  512
#define HID   256
#define OUTF  16
#define NPAD  100096   // 782 * 128

typedef unsigned int u32;
typedef __bf16 bfrag  __attribute__((ext_vector_type(8)));
typedef float  f32x4  __attribute__((ext_vector_type(4)));
typedef short  s16x8  __attribute__((ext_vector_type(8)));

__device__ __forceinline__ u32 rotl32(u32 x, int r){ return (x<<r)|(x>>(32-r)); }

// JAX threefry2x32, key=(0,42), counts=(0,i). keep <=> top bit of (x0^x1)==0.
__device__ __forceinline__ bool drop_keep(u32 i){
    const u32 ks0 = 0u, ks1 = 42u, ks2 = 0x1BD11BDAu ^ 0u ^ 42u;
    u32 x0 = 0u + ks0;
    u32 x1 = i  + ks1;
#define TFR(r) { x0 += x1; x1 = rotl32(x1,(r)); x1 ^= x0; }
    TFR(13) TFR(15) TFR(26) TFR(6)   x0 += ks1; x1 += ks2 + 1u;
    TFR(17) TFR(29) TFR(16) TFR(24)  x0 += ks2; x1 += ks0 + 2u;
    TFR(13) TFR(15) TFR(26) TFR(6)   x0 += ks0; x1 += ks1 + 3u;
    TFR(17) TFR(29) TFR(16) TFR(24)  x0 += ks1; x1 += ks2 + 4u;
    TFR(13) TFR(15) TFR(26) TFR(6)   x0 += ks2; x1 += ks0 + 5u;
#undef TFR
    return ((x0 ^ x1) >> 31) == 0u;
}

__device__ __forceinline__ short f2b(float f){
    union { float f; u32 u; } v; v.f = f;
    u32 r = (v.u + 0x7FFFu + ((v.u >> 16) & 1u)) >> 16;   // RNE
    return (short)r;
}
__device__ __forceinline__ float blo(u32 u){ union{u32 u; float f;} v; v.u = u << 16;        return v.f; }
__device__ __forceinline__ float bhi(u32 u){ union{u32 u; float f;} v; v.u = u & 0xFFFF0000u; return v.f; }

__device__ __forceinline__ void gll16(const void* g, void* l){
    __builtin_amdgcn_global_load_lds((const __attribute__((address_space(1))) void*)g,
                                     (__attribute__((address_space(3))) void*)l, 16, 0, 0);
}

// ---------------- degrees / CSR ----------------

__global__ __launch_bounds__(256) void hist_kernel(const int* __restrict__ src,
                                                   const int* __restrict__ dst,
                                                   int* deg_out, int* deg_in){
    int i = blockIdx.x * blockDim.x + threadIdx.x;
    if (i < NE) {
        atomicAdd(&deg_out[src[i]], 1);
        atomicAdd(&deg_in[dst[i]], 1);
    }
}

__global__ __launch_bounds__(256) void finalize_deg(const int* deg_out, const int* deg_in,
                                                    float* isdo, float* isdi){
    int i = blockIdx.x * blockDim.x + threadIdx.x;
    if (i < NN) {
        isdo[i] = rsqrtf(fmaxf((float)deg_out[i], 1.0f));
        isdi[i] = rsqrtf(fmaxf((float)deg_in[i], 1.0f));
    }
}

// block-local exclusive scan (1024/block) + block sums
__global__ __launch_bounds__(1024) void scan_block(const int* __restrict__ deg,
                                                   int* __restrict__ out,
                                                   int* __restrict__ bsum){
    __shared__ int wsum[16];
    int t = threadIdx.x;
    int i = blockIdx.x * 1024 + t;
    int v = (i < NN) ? deg[i] : 0;
    int lane = t & 63, w = t >> 6;
    int s = v;
    #pragma unroll
    for (int off = 1; off < 64; off <<= 1) {
        int u = __shfl_up(s, off);
        if (lane >= off) s += u;
    }
    if (lane == 63) wsum[w] = s;
    __syncthreads();
    if (w == 0) {
        int x = (lane < 16) ? wsum[lane] : 0;
        #pragma unroll
        for (int off = 1; off < 16; off <<= 1) {
            int u = __shfl_up(x, off);
            if (lane >= off) x += u;
        }
        if (lane < 16) wsum[lane] = x;
    }
    __syncthreads();
    int woff = (w == 0) ? 0 : wsum[w - 1];
    if (i < NN) out[i] = woff + s - v;
    if (t == 0) bsum[blockIdx.x] = wsum[15];
}

__global__ __launch_bounds__(128) void scan_tops(int* bsum, int nb){
    __shared__ int sh[128];
    int t = threadIdx.x;
    int v = (t < nb) ? bsum[t] : 0;
    sh[t] = v;
    __syncthreads();
    for (int off = 1; off < 128; off <<= 1) {
        int a = (t >= off) ? sh[t - off] : 0;
        __syncthreads();
        sh[t] += a;
        __syncthreads();
    }
    if (t < nb) bsum[t] = sh[t] - v;   // exclusive
}

__global__ __launch_bounds__(256) void scan_add(int* __restrict__ row_ptr,
                                                int* __restrict__ cursor,
                                                const int* __restrict__ bsum){
    int i = blockIdx.x * blockDim.x + threadIdx.x;
    if (i < NN) {
        int r = row_ptr[i] + bsum[i >> 10];
        row_ptr[i] = r;
        cursor[i] = r;
    }
    if (i == 0) row_ptr[NN] = NE;
}

__global__ __launch_bounds__(256) void fill_csr(const int* __restrict__ src,
                                                const int* __restrict__ dst,
                                                int* cursor, int* __restrict__ col_src){
    int i = blockIdx.x * blockDim.x + threadIdx.x;
    if (i < NE) {
        int pos = atomicAdd(&cursor[dst[i]], 1);
        col_src[pos] = src[i];
    }
}

// ---------------- conversions ----------------

// Xb[m][k] = bf16(X[m][k] * isdo[m]); zero pad rows. one thread = 8 elements
__global__ __launch_bounds__(256) void convert_x(const float* __restrict__ X,
                                                 const float* __restrict__ isdo,
                                                 short* __restrict__ Xb){
    int idx8 = blockIdx.x * 256 + threadIdx.x;   // NPAD*512/8 total
    int m = idx8 >> 6;
    s16x8 r;
    if (m < NN) {
        float s = isdo[m];
        const float4* p = (const float4*)(X + (size_t)idx8 * 8);
        float4 a = p[0], b = p[1];
        r[0] = f2b(a.x * s); r[1] = f2b(a.y * s); r[2] = f2b(a.z * s); r[3] = f2b(a.w * s);
        r[4] = f2b(b.x * s); r[5] = f2b(b.y * s); r[6] = f2b(b.z * s); r[7] = f2b(b.w * s);
    } else {
        r = (s16x8)0;
    }
    *(s16x8*)(Xb + (size_t)idx8 * 8) = r;
}

// WT[n][k] = bf16(W[k][n]);  W: Kd x Nd row-major
template<int Kd, int Nd>
__global__ __launch_bounds__(256) void convert_wt(const float* __restrict__ W,
                                                  short* __restrict__ WT){
    int i = blockIdx.x * 256 + threadIdx.x;   // over Nd*Kd, k fastest
    if (i >= Kd * Nd) return;
    int n = i / Kd, k = i - n * Kd;
    WT[i] = f2b(W[(size_t)k * Nd + n]);
}

// ---------------- MFMA GEMM: C = A * BT^T (A: NPAD x K bf16, BT: 256 x K bf16) ----------------
// 128x128 tile, 4 waves (2x2), BK=32, LDS chunk layout [kb][row][8]
template<int K>
__global__ __launch_bounds__(256) void gemm_bt(const short* __restrict__ A,
                                               const short* __restrict__ BT,
                                               short* __restrict__ C){
    __shared__ short As[4096];   // 4 kb-blocks * 128 rows * 8
    __shared__ short Bs[4096];

    const int t = threadIdx.x;
    const int wave = t >> 6, lane = t & 63;
    const int bm = blockIdx.x * 128;
    const int bn = blockIdx.y * 128;

    // staging: wave stages chunks [wave*128, wave*128+128)
    const int ch0 = wave * 128 + lane;
    const int ch1 = ch0 + 64;
    const int kb0 = ch0 >> 7, r0 = ch0 & 127;
    const int kb1 = ch1 >> 7, r1 = ch1 & 127;
    const short* pa0 = A  + (size_t)(bm + r0) * K + kb0 * 8;
    const short* pa1 = A  + (size_t)(bm + r1) * K + kb1 * 8;
    const short* pb0 = BT + (size_t)(bn + r0) * K + kb0 * 8;
    const short* pb1 = BT + (size_t)(bn + r1) * K + kb1 * 8;
    short* lA0 = As + (size_t)(wave * 128) * 8;
    short* lA1 = As + (size_t)(wave * 128 + 64) * 8;
    short* lB0 = Bs + (size_t)(wave * 128) * 8;
    short* lB1 = Bs + (size_t)(wave * 128 + 64) * 8;

    // fragment read base: [kb=lane>>4][row = wrow + m*16 + (lane&15)]
    const int wr = (wave >> 1) * 64, wc = (wave & 1) * 64;
    const short* fa = As + (size_t)((lane >> 4) * 128 + wr + (lane & 15)) * 8;
    const short* fb = Bs + (size_t)((lane >> 4) * 128 + wc + (lane & 15)) * 8;

    f32x4 acc[4][4];
    #pragma unroll
    for (int m = 0; m < 4; ++m)
        #pragma unroll
        for (int n = 0; n < 4; ++n) acc[m][n] = (f32x4)0.0f;

    for (int k0 = 0; k0 < K; k0 += 32) {
        gll16(pa0 + k0, lA0);
        gll16(pa1 + k0, lA1);
        gll16(pb0 + k0, lB0);
        gll16(pb1 + k0, lB1);
        __syncthreads();

        bfrag af[4], bfg[4];
        #pragma unroll
        for (int m = 0; m < 4; ++m) af[m]  = *(const bfrag*)(fa + m * 128);
        #pragma unroll
        for (int n = 0; n < 4; ++n) bfg[n] = *(const bfrag*)(fb + n * 128);
        #pragma unroll
        for (int m = 0; m < 4; ++m)
            #pragma unroll
            for (int n = 0; n < 4; ++n)
                acc[m][n] = __builtin_amdgcn_mfma_f32_16x16x32_bf16(af[m], bfg[n], acc[m][n], 0, 0, 0);
        __syncthreads();
    }

    // C/D layout: col = lane&15, row = (lane>>4)*4 + r
    const int crow0 = bm + wr + (lane >> 4) * 4;
    const int ccol0 = bn + wc + (lane & 15);
    #pragma unroll
    for (int m = 0; m < 4; ++m)
        #pragma unroll
        for (int n = 0; n < 4; ++n)
            #pragma unroll
            for (int r = 0; r < 4; ++r)
                C[(size_t)(crow0 + m * 16 + r) * HID + ccol0 + n * 16] = f2b(acc[m][n][r]);
}

// ---------------- gather aggregation (bf16 in/out) ----------------
// MODE 0: h = relu(agg*isdi + bias) -> dropout -> * isdo  (feeds GEMM2)
// MODE 1: h = agg*isdi + bias                              (final h2)
template<int MODE>
__global__ __launch_bounds__(256) void gather_agg(const short* __restrict__ H,
                                                  const int* __restrict__ rp,
                                                  const int* __restrict__ cs,
                                                  const float* __restrict__ isdi,
                                                  const float* __restrict__ isdo,
                                                  const float* __restrict__ bias,
                                                  short* __restrict__ out){
    int node = blockIdx.x * 4 + (threadIdx.x >> 6);
    int lane = threadIdx.x & 63;
    if (node >= NN) return;
    int e   = rp[node];
    int end = rp[node + 1];
    const int off = lane * 4;

    float a0=0.f,a1=0.f,a2=0.f,a3=0.f;
    float c0=0.f,c1=0.f,c2=0.f,c3=0.f;

    for (; e + 4 <= end; e += 4) {
        int s0 = cs[e], s1 = cs[e+1], s2 = cs[e+2], s3 = cs[e+3];
        uint2 u0 = *(const uint2*)(H + (size_t)s0 * HID + off);
        uint2 u1 = *(const uint2*)(H + (size_t)s1 * HID + off);
        uint2 u2 = *(const uint2*)(H + (size_t)s2 * HID + off);
        uint2 u3 = *(const uint2*)(H + (size_t)s3 * HID + off);
        a0 += blo(u0.x) + blo(u2.x); a1 += bhi(u0.x) + bhi(u2.x);
        a2 += blo(u0.y) + blo(u2.y); a3 += bhi(u0.y) + bhi(u2.y);
        c0 += blo(u1.x) + blo(u3.x); c1 += bhi(u1.x) + bhi(u3.x);
        c2 += blo(u1.y) + blo(u3.y); c3 += bhi(u1.y) + bhi(u3.y);
    }
    for (; e < end; ++e) {
        int s0 = cs[e];
        uint2 u0 = *(const uint2*)(H + (size_t)s0 * HID + off);
        a0 += blo(u0.x); a1 += bhi(u0.x); a2 += blo(u0.y); a3 += bhi(u0.y);
    }
    a0 += c0; a1 += c1; a2 += c2; a3 += c3;

    float sd = isdi[node];
    float4 b = *(const float4*)(bias + off);
    float h0 = a0 * sd + b.x;
    float h1 = a1 * sd + b.y;
    float h2 = a2 * sd + b.z;
    float h3 = a3 * sd + b.w;

    if (MODE == 0) {
        float so2 = 2.0f * isdo[node];
        u32 base = (u32)node * HID + off;
        h0 = drop_keep(base+0) ? fmaxf(h0, 0.f) * so2 : 0.f;
        h1 = drop_keep(base+1) ? fmaxf(h1, 0.f) * so2 : 0.f;
        h2 = drop_keep(base+2) ? fmaxf(h2, 0.f) * so2 : 0.f;
        h3 = drop_keep(base+3) ? fmaxf(h3, 0.f) * so2 : 0.f;
    }

    uint2 w;
    w.x = ((u32)(unsigned short)f2b(h1) << 16) | (u32)(unsigned short)f2b(h0);
    w.y = ((u32)(unsigned short)f2b(h3) << 16) | (u32)(unsigned short)f2b(h2);
    *(uint2*)(out + (size_t)node * HID + off) = w;
}

// ---------------- head: out[n][k] = sum_j H2[n][j]*W3[j][k] + b3[k] ----------------
__global__ __launch_bounds__(256) void head_kernel(const short* __restrict__ H2,
                                                   const float* __restrict__ W3,
                                                   const float* __restrict__ b3,
                                                   float* __restrict__ out){
    __shared__ float W3s[HID * OUTF];
    __shared__ short rows[16][HID + 8];
    int t = threadIdx.x;
    for (int i = t; i < HID * OUTF; i += 256) W3s[i] = W3[i];
    const int n0 = blockIdx.x * 16;
    for (int c = t; c < 16 * 32; c += 256) {        // 32 chunks of 8 shorts per row
        int r = c >> 5, cc = c & 31;
        *(s16x8*)(&rows[r][cc * 8]) = *(const s16x8*)(H2 + (size_t)(n0 + r) * HID + cc * 8);
    }
    __syncthreads();
    int nl = t >> 4, k = t & 15;
    float acc = 0.0f;
    #pragma unroll 4
    for (int j = 0; j < HID; ++j)
        acc += blo((u32)(unsigned short)rows[nl][j]) * W3s[j * OUTF + k];
    out[(size_t)(n0 + nl) * OUTF + k] = acc + b3[k];
}

extern "C" void kernel_launch(void* const* d_in, const int* in_sizes, int n_in,
                              void* d_out, int out_size, void* d_ws, size_t ws_size,
                              hipStream_t stream) {
    const float* X   = (const float*)d_in[0];
    const int*   src = (const int*)  d_in[1];
    const int*   dst = (const int*)  d_in[2];
    const float* W1  = (const float*)d_in[3];
    const float* b1  = (const float*)d_in[4];
    const float* W2  = (const float*)d_in[5];
    const float* b2  = (const float*)d_in[6];
    const float* W3  = (const float*)d_in[7];
    const float* b3  = (const float*)d_in[8];
    float* out = (float*)d_out;

    char* ws = (char*)d_ws;
    size_t o = 0;
    int*   deg_out = (int*)  (ws + o); o += (size_t)NN * 4;
    int*   deg_in  = (int*)  (ws + o); o += (size_t)NN * 4;
    float* isdo    = (float*)(ws + o); o += (size_t)NN * 4;
    float* isdi    = (float*)(ws + o); o += (size_t)NN * 4;
    int*   row_ptr = (int*)  (ws + o); o += (size_t)(NN + 1) * 4;
    int*   cursor  = (int*)  (ws + o); o += (size_t)NN * 4;
    int*   bsum    = (int*)  (ws + o); o += 512;
    int*   col_src = (int*)  (ws + o); o += (size_t)NE * 4;
    o = (o + 255) & ~(size_t)255;
    short* W1t = (short*)(ws + o); o += (size_t)IN_F * HID * 2;
    short* W2t = (short*)(ws + o); o += (size_t)HID * HID * 2;
    o = (o + 255) & ~(size_t)255;
    short* Xb  = (short*)(ws + o); o += (size_t)NPAD * IN_F * 2;   // also reused as h2pre
    short* hA  = (short*)(ws + o); o += (size_t)NPAD * HID * 2;    // h0, later h2
    short* hB  = (short*)(ws + o); o += (size_t)NPAD * HID * 2;    // h1*isdo
    if (ws_size < o) return;
    short* h2pre = Xb;   // reuse after GEMM1 consumed Xb
    short* h2    = hA;   // reuse after gather1 consumed h0

    // ---- degrees + CSR ----
    hipMemsetAsync(deg_out, 0, (size_t)NN * 4 * 2, stream);
    hist_kernel<<<(NE + 255) / 256, 256, 0, stream>>>(src, dst, deg_out, deg_in);
    finalize_deg<<<(NN + 255) / 256, 256, 0, stream>>>(deg_out, deg_in, isdo, isdi);
    const int NB = (NN + 1023) / 1024;   // 98
    scan_block<<<NB, 1024, 0, stream>>>(deg_in, row_ptr, bsum);
    scan_tops<<<1, 128, 0, stream>>>(bsum, NB);
    scan_add<<<(NN + 255) / 256, 256, 0, stream>>>(row_ptr, cursor, bsum);
    fill_csr<<<(NE + 255) / 256, 256, 0, stream>>>(src, dst, cursor, col_src);

    // ---- conversions ----
    convert_x<<<NPAD * IN_F / 8 / 256, 256, 0, stream>>>(X, isdo, Xb);
    convert_wt<IN_F, HID><<<IN_F * HID / 256, 256, 0, stream>>>(W1, W1t);
    convert_wt<HID, HID><<<HID * HID / 256, 256, 0, stream>>>(W2, W2t);

    dim3 ggrid(NPAD / 128, 2);

    // ---- layer 1 ----
    gemm_bt<IN_F><<<ggrid, 256, 0, stream>>>(Xb, W1t, hA);                    // h0
    gather_agg<0><<<NN / 4, 256, 0, stream>>>(hA, row_ptr, col_src, isdi, isdo, b1, hB);

    // ---- layer 2 ----
    gemm_bt<HID><<<ggrid, 256, 0, stream>>>(hB, W2t, h2pre);
    gather_agg<1><<<NN / 4, 256, 0, stream>>>(h2pre, row_ptr, col_src, isdi, isdo, b2, h2);

    // ---- head ----
    head_kernel<<<NN / 16, 256, 0, stream>>>(h2, W3, b3, out);
}

// Round 4
// 575.724 us; speedup vs baseline: 19.8835x; 1.2072x over previous
//
#include <hip/hip_runtime.h>
#include <stdint.h>

#define NN    100000
#define NE    1600000
#define IN_F  512
#define HID   256
#define OUTF  16
#define NPAD  100096   // 782 * 128
#define NBK   391      // ceil(NN/256) coarse buckets (dst>>8)
#define EPB   8192     // edges per block in bucket_scatter

typedef unsigned int u32;
typedef __bf16 bfrag  __attribute__((ext_vector_type(8)));
typedef float  f32x4  __attribute__((ext_vector_type(4)));
typedef short  s16x8  __attribute__((ext_vector_type(8)));

__device__ __forceinline__ u32 rotl32(u32 x, int r){ return (x<<r)|(x>>(32-r)); }

// JAX threefry2x32, key=(0,42), counts=(0,i). keep <=> top bit of (x0^x1)==0.
__device__ __forceinline__ bool drop_keep(u32 i){
    const u32 ks0 = 0u, ks1 = 42u, ks2 = 0x1BD11BDAu ^ 0u ^ 42u;
    u32 x0 = 0u + ks0;
    u32 x1 = i  + ks1;
#define TFR(r) { x0 += x1; x1 = rotl32(x1,(r)); x1 ^= x0; }
    TFR(13) TFR(15) TFR(26) TFR(6)   x0 += ks1; x1 += ks2 + 1u;
    TFR(17) TFR(29) TFR(16) TFR(24)  x0 += ks2; x1 += ks0 + 2u;
    TFR(13) TFR(15) TFR(26) TFR(6)   x0 += ks0; x1 += ks1 + 3u;
    TFR(17) TFR(29) TFR(16) TFR(24)  x0 += ks1; x1 += ks2 + 4u;
    TFR(13) TFR(15) TFR(26) TFR(6)   x0 += ks2; x1 += ks0 + 5u;
#undef TFR
    return ((x0 ^ x1) >> 31) == 0u;
}

__device__ __forceinline__ short f2b(float f){
    union { float f; u32 u; } v; v.f = f;
    u32 r = (v.u + 0x7FFFu + ((v.u >> 16) & 1u)) >> 16;   // RNE
    return (short)r;
}
__device__ __forceinline__ float blo(u32 u){ union{u32 u; float f;} v; v.u = u << 16;         return v.f; }
__device__ __forceinline__ float bhi(u32 u){ union{u32 u; float f;} v; v.u = u & 0xFFFF0000u; return v.f; }

__device__ __forceinline__ void gll16(const void* g, void* l){
    __builtin_amdgcn_global_load_lds((const __attribute__((address_space(1))) void*)g,
                                     (__attribute__((address_space(3))) void*)l, 16, 0, 0);
}

// ---------------- deg_out histogram ----------------

__global__ __launch_bounds__(256) void hist_kernel(const int* __restrict__ src,
                                                   int* deg_out){
    int i = blockIdx.x * blockDim.x + threadIdx.x;
    if (i < NE) atomicAdd(&deg_out[src[i]], 1);
}

// isdo from deg_out, isdi from row_ptr diff
__global__ __launch_bounds__(256) void finalize_deg(const int* __restrict__ deg_out,
                                                    const int* __restrict__ row_ptr,
                                                    float* isdo, float* isdi){
    int i = blockIdx.x * blockDim.x + threadIdx.x;
    if (i < NN) {
        isdo[i] = rsqrtf(fmaxf((float)deg_out[i], 1.0f));
        isdi[i] = rsqrtf(fmaxf((float)(row_ptr[i + 1] - row_ptr[i]), 1.0f));
    }
}

// ---------------- bucket-sort CSR build ----------------

// Pass A: coarse histogram of dst>>8
__global__ __launch_bounds__(256) void bucket_hist(const int* __restrict__ dst,
                                                   int* __restrict__ bcnt){
    __shared__ int h[NBK];
    int t = threadIdx.x;
    for (int i = t; i < NBK; i += 256) h[i] = 0;
    __syncthreads();
    for (int i = blockIdx.x * 256 + t; i < NE; i += gridDim.x * 256)
        atomicAdd(&h[dst[i] >> 8], 1);
    __syncthreads();
    for (int i = t; i < NBK; i += 256)
        if (h[i]) atomicAdd(&bcnt[i], h[i]);
}

// single block: exclusive scan of bcnt -> bbase, bcur
__global__ __launch_bounds__(512) void bucket_scan(const int* __restrict__ bcnt,
                                                   int* __restrict__ bbase,
                                                   int* __restrict__ bcur,
                                                   int* __restrict__ row_ptr){
    __shared__ int sh[512];
    int t = threadIdx.x;
    int v = (t < NBK) ? bcnt[t] : 0;
    sh[t] = v;
    __syncthreads();
    for (int off = 1; off < 512; off <<= 1) {
        int a = (t >= off) ? sh[t - off] : 0;
        __syncthreads();
        sh[t] += a;
        __syncthreads();
    }
    int excl = sh[t] - v;
    if (t < NBK) { bbase[t] = excl; bcur[t] = excl; }
    if (t == 0)  { bbase[NBK] = NE; row_ptr[NN] = NE; }
}

// Pass B: scatter (dst,src) pairs into coarse-bucket regions
__global__ __launch_bounds__(256) void bucket_scatter(const int* __restrict__ src,
                                                      const int* __restrict__ dst,
                                                      int* bcur, uint2* __restrict__ tmp){
    __shared__ int lh[NBK];   // local count, then local cursor
    __shared__ int lb[NBK];   // reserved global base
    int t = threadIdx.x;
    for (int i = t; i < NBK; i += 256) lh[i] = 0;
    __syncthreads();
    const int e0 = blockIdx.x * EPB;
    for (int k = t; k < EPB; k += 256) {
        int e = e0 + k;
        if (e < NE) atomicAdd(&lh[dst[e] >> 8], 1);
    }
    __syncthreads();
    for (int i = t; i < NBK; i += 256) {
        int c = lh[i];
        if (c) lb[i] = atomicAdd(&bcur[i], c);
        lh[i] = 0;
    }
    __syncthreads();
    for (int k = t; k < EPB; k += 256) {
        int e = e0 + k;
        if (e < NE) {
            int d = dst[e], b = d >> 8;
            int r = atomicAdd(&lh[b], 1);
            tmp[lb[b] + r] = make_uint2((u32)d, (u32)src[e]);
        }
    }
}

// Pass C: per-bucket counting sort by low 8 bits of dst; emits row_ptr and col_src
__global__ __launch_bounds__(256) void bucket_finalize(const uint2* __restrict__ tmp,
                                                       const int* __restrict__ bbase,
                                                       int* __restrict__ row_ptr,
                                                       int* __restrict__ col_src){
    __shared__ int h[256];
    __shared__ int wtot[4];
    const int t = threadIdx.x;
    const int b = blockIdx.x;
    const int base = bbase[b];
    const int cnt  = bbase[b + 1] - base;
    h[t] = 0;
    __syncthreads();
    for (int k = t; k < cnt; k += 256)
        atomicAdd(&h[tmp[base + k].x & 255u], 1);
    __syncthreads();
    int v = h[t];
    int lane = t & 63, w = t >> 6;
    int s = v;
    #pragma unroll
    for (int off = 1; off < 64; off <<= 1) {
        int u = __shfl_up(s, off);
        if (lane >= off) s += u;
    }
    if (lane == 63) wtot[w] = s;
    __syncthreads();
    int woff = 0;
    #pragma unroll
    for (int i = 0; i < 4; ++i) woff += (i < w) ? wtot[i] : 0;
    int excl = woff + s - v;
    int d = (b << 8) + t;
    if (d < NN) row_ptr[d] = base + excl;
    h[t] = excl;              // reuse as cursor
    __syncthreads();
    for (int k = t; k < cnt; k += 256) {
        uint2 p = tmp[base + k];
        int r = atomicAdd(&h[p.x & 255u], 1);
        col_src[base + r] = (int)p.y;
    }
}

// ---------------- conversions ----------------

__global__ __launch_bounds__(256) void convert_x(const float* __restrict__ X,
                                                 const float* __restrict__ isdo,
                                                 short* __restrict__ Xb){
    int idx8 = blockIdx.x * 256 + threadIdx.x;
    int m = idx8 >> 6;
    s16x8 r;
    if (m < NN) {
        float s = isdo[m];
        const float4* p = (const float4*)(X + (size_t)idx8 * 8);
        float4 a = p[0], b = p[1];
        r[0] = f2b(a.x * s); r[1] = f2b(a.y * s); r[2] = f2b(a.z * s); r[3] = f2b(a.w * s);
        r[4] = f2b(b.x * s); r[5] = f2b(b.y * s); r[6] = f2b(b.z * s); r[7] = f2b(b.w * s);
    } else {
        r = (s16x8)0;
    }
    *(s16x8*)(Xb + (size_t)idx8 * 8) = r;
}

template<int Kd, int Nd>
__global__ __launch_bounds__(256) void convert_wt(const float* __restrict__ W,
                                                  short* __restrict__ WT){
    int i = blockIdx.x * 256 + threadIdx.x;
    if (i >= Kd * Nd) return;
    int n = i / Kd, k = i - n * Kd;
    WT[i] = f2b(W[(size_t)k * Nd + n]);
}

// ---------------- MFMA GEMM: C = A * BT^T ----------------
template<int K>
__global__ __launch_bounds__(256) void gemm_bt(const short* __restrict__ A,
                                               const short* __restrict__ BT,
                                               short* __restrict__ C){
    __shared__ short As[4096];
    __shared__ short Bs[4096];

    const int t = threadIdx.x;
    const int wave = t >> 6, lane = t & 63;
    const int bm = blockIdx.x * 128;
    const int bn = blockIdx.y * 128;

    const int ch0 = wave * 128 + lane;
    const int ch1 = ch0 + 64;
    const int kb0 = ch0 >> 7, r0 = ch0 & 127;
    const int kb1 = ch1 >> 7, r1 = ch1 & 127;
    const short* pa0 = A  + (size_t)(bm + r0) * K + kb0 * 8;
    const short* pa1 = A  + (size_t)(bm + r1) * K + kb1 * 8;
    const short* pb0 = BT + (size_t)(bn + r0) * K + kb0 * 8;
    const short* pb1 = BT + (size_t)(bn + r1) * K + kb1 * 8;
    short* lA0 = As + (size_t)(wave * 128) * 8;
    short* lA1 = As + (size_t)(wave * 128 + 64) * 8;
    short* lB0 = Bs + (size_t)(wave * 128) * 8;
    short* lB1 = Bs + (size_t)(wave * 128 + 64) * 8;

    const int wr = (wave >> 1) * 64, wc = (wave & 1) * 64;
    const short* fa = As + (size_t)((lane >> 4) * 128 + wr + (lane & 15)) * 8;
    const short* fb = Bs + (size_t)((lane >> 4) * 128 + wc + (lane & 15)) * 8;

    f32x4 acc[4][4];
    #pragma unroll
    for (int m = 0; m < 4; ++m)
        #pragma unroll
        for (int n = 0; n < 4; ++n) acc[m][n] = (f32x4)0.0f;

    for (int k0 = 0; k0 < K; k0 += 32) {
        gll16(pa0 + k0, lA0);
        gll16(pa1 + k0, lA1);
        gll16(pb0 + k0, lB0);
        gll16(pb1 + k0, lB1);
        __syncthreads();

        bfrag af[4], bfg[4];
        #pragma unroll
        for (int m = 0; m < 4; ++m) af[m]  = *(const bfrag*)(fa + m * 128);
        #pragma unroll
        for (int n = 0; n < 4; ++n) bfg[n] = *(const bfrag*)(fb + n * 128);
        #pragma unroll
        for (int m = 0; m < 4; ++m)
            #pragma unroll
            for (int n = 0; n < 4; ++n)
                acc[m][n] = __builtin_amdgcn_mfma_f32_16x16x32_bf16(af[m], bfg[n], acc[m][n], 0, 0, 0);
        __syncthreads();
    }

    const int crow0 = bm + wr + (lane >> 4) * 4;
    const int ccol0 = bn + wc + (lane & 15);
    #pragma unroll
    for (int m = 0; m < 4; ++m)
        #pragma unroll
        for (int n = 0; n < 4; ++n)
            #pragma unroll
            for (int r = 0; r < 4; ++r)
                C[(size_t)(crow0 + m * 16 + r) * HID + ccol0 + n * 16] = f2b(acc[m][n][r]);
}

// ---------------- gather aggregation (bf16 in/out, readlane edge broadcast) ----------------
template<int MODE>
__global__ __launch_bounds__(256) void gather_agg(const short* __restrict__ H,
                                                  const int* __restrict__ rp,
                                                  const int* __restrict__ cs,
                                                  const float* __restrict__ isdi,
                                                  const float* __restrict__ isdo,
                                                  const float* __restrict__ bias,
                                                  short* __restrict__ out){
    int node = blockIdx.x * 4 + (threadIdx.x >> 6);
    int lane = threadIdx.x & 63;
    if (node >= NN) return;
    const int e0  = rp[node];
    const int end = rp[node + 1];
    const u32 off = (u32)lane * 8;   // byte offset of this lane's uint2 in a 512B row

    float a0 = 0.f, a1 = 0.f, a2 = 0.f, a3 = 0.f;

    for (int eb = e0; eb < end; eb += 64) {
        int m = end - eb; if (m > 64) m = 64;
        int idx = eb + (lane < m ? lane : m - 1);
        int s_my = cs[idx];
        int k = 0;
        for (; k + 4 <= m; k += 4) {
            int s0 = __builtin_amdgcn_readlane(s_my, k + 0);
            int s1 = __builtin_amdgcn_readlane(s_my, k + 1);
            int s2 = __builtin_amdgcn_readlane(s_my, k + 2);
            int s3 = __builtin_amdgcn_readlane(s_my, k + 3);
            uint2 u0 = *(const uint2*)((const char*)H + (((size_t)(u32)s0) << 9) + off);
            uint2 u1 = *(const uint2*)((const char*)H + (((size_t)(u32)s1) << 9) + off);
            uint2 u2 = *(const uint2*)((const char*)H + (((size_t)(u32)s2) << 9) + off);
            uint2 u3 = *(const uint2*)((const char*)H + (((size_t)(u32)s3) << 9) + off);
            a0 += blo(u0.x) + blo(u2.x); a1 += bhi(u0.x) + bhi(u2.x);
            a2 += blo(u0.y) + blo(u2.y); a3 += bhi(u0.y) + bhi(u2.y);
            a0 += blo(u1.x) + blo(u3.x); a1 += bhi(u1.x) + bhi(u3.x);
            a2 += blo(u1.y) + blo(u3.y); a3 += bhi(u1.y) + bhi(u3.y);
        }
        for (; k < m; ++k) {
            int s0 = __builtin_amdgcn_readlane(s_my, k);
            uint2 u0 = *(const uint2*)((const char*)H + (((size_t)(u32)s0) << 9) + off);
            a0 += blo(u0.x); a1 += bhi(u0.x); a2 += blo(u0.y); a3 += bhi(u0.y);
        }
    }

    float sd = isdi[node];
    float4 b = *(const float4*)((const char*)bias + off * 4);
    float h0 = a0 * sd + b.x;
    float h1 = a1 * sd + b.y;
    float h2 = a2 * sd + b.z;
    float h3 = a3 * sd + b.w;

    if (MODE == 0) {
        float so2 = 2.0f * isdo[node];
        u32 base = (u32)node * HID + (u32)lane * 4;
        h0 = drop_keep(base + 0) ? fmaxf(h0, 0.f) * so2 : 0.f;
        h1 = drop_keep(base + 1) ? fmaxf(h1, 0.f) * so2 : 0.f;
        h2 = drop_keep(base + 2) ? fmaxf(h2, 0.f) * so2 : 0.f;
        h3 = drop_keep(base + 3) ? fmaxf(h3, 0.f) * so2 : 0.f;
    }

    uint2 wv;
    wv.x = ((u32)(unsigned short)f2b(h1) << 16) | (u32)(unsigned short)f2b(h0);
    wv.y = ((u32)(unsigned short)f2b(h3) << 16) | (u32)(unsigned short)f2b(h2);
    *(uint2*)((char*)out + (size_t)node * 512 + off) = wv;
}

// ---------------- head ----------------
__global__ __launch_bounds__(256) void head_kernel(const short* __restrict__ H2,
                                                   const float* __restrict__ W3,
                                                   const float* __restrict__ b3,
                                                   float* __restrict__ out){
    __shared__ float W3s[HID * OUTF];
    __shared__ short rows[16][HID + 8];
    int t = threadIdx.x;
    for (int i = t; i < HID * OUTF; i += 256) W3s[i] = W3[i];
    const int n0 = blockIdx.x * 16;
    for (int c = t; c < 16 * 32; c += 256) {
        int r = c >> 5, cc = c & 31;
        *(s16x8*)(&rows[r][cc * 8]) = *(const s16x8*)(H2 + (size_t)(n0 + r) * HID + cc * 8);
    }
    __syncthreads();
    int nl = t >> 4, k = t & 15;
    float acc = 0.0f;
    #pragma unroll 4
    for (int j = 0; j < HID; ++j)
        acc += blo((u32)(unsigned short)rows[nl][j]) * W3s[j * OUTF + k];
    out[(size_t)(n0 + nl) * OUTF + k] = acc + b3[k];
}

extern "C" void kernel_launch(void* const* d_in, const int* in_sizes, int n_in,
                              void* d_out, int out_size, void* d_ws, size_t ws_size,
                              hipStream_t stream) {
    const float* X   = (const float*)d_in[0];
    const int*   src = (const int*)  d_in[1];
    const int*   dst = (const int*)  d_in[2];
    const float* W1  = (const float*)d_in[3];
    const float* b1  = (const float*)d_in[4];
    const float* W2  = (const float*)d_in[5];
    const float* b2  = (const float*)d_in[6];
    const float* W3  = (const float*)d_in[7];
    const float* b3  = (const float*)d_in[8];
    float* out = (float*)d_out;

    char* ws = (char*)d_ws;
    size_t o = 0;
    int*   deg_out = (int*)  (ws + o); o += (size_t)NN * 4;
    int*   bcnt    = (int*)  (ws + o); o += (size_t)NBK * 4;       // memset with deg_out
    float* isdo    = (float*)(ws + o); o += (size_t)NN * 4;
    float* isdi    = (float*)(ws + o); o += (size_t)NN * 4;
    int*   row_ptr = (int*)  (ws + o); o += (size_t)(NN + 1) * 4;
    int*   bbase   = (int*)  (ws + o); o += (size_t)(NBK + 1) * 4;
    int*   bcur    = (int*)  (ws + o); o += (size_t)NBK * 4;
    int*   col_src = (int*)  (ws + o); o += (size_t)NE * 4;
    o = (o + 255) & ~(size_t)255;
    short* W1t = (short*)(ws + o); o += (size_t)IN_F * HID * 2;
    short* W2t = (short*)(ws + o); o += (size_t)HID * HID * 2;
    o = (o + 255) & ~(size_t)255;
    short* Xb  = (short*)(ws + o); o += (size_t)NPAD * IN_F * 2;
    short* hA  = (short*)(ws + o); o += (size_t)NPAD * HID * 2;
    short* hB  = (short*)(ws + o); o += (size_t)NPAD * HID * 2;
    if (ws_size < o) return;
    short* h2pre = Xb;
    short* h2    = hA;
    uint2* tmp   = (uint2*)hB;   // alias: tmp consumed before hB is first written

    const size_t zlen = (size_t)NN * 4 + (size_t)NBK * 4;  // deg_out + bcnt contiguous
    hipMemsetAsync(deg_out, 0, zlen, stream);

    // ---- CSR build (bucket sort) + degrees ----
    hist_kernel<<<(NE + 255) / 256, 256, 0, stream>>>(src, deg_out);
    bucket_hist<<<256, 256, 0, stream>>>(dst, bcnt);
    bucket_scan<<<1, 512, 0, stream>>>(bcnt, bbase, bcur, row_ptr);
    bucket_scatter<<<(NE + EPB - 1) / EPB, 256, 0, stream>>>(src, dst, bcur, tmp);
    bucket_finalize<<<NBK, 256, 0, stream>>>(tmp, bbase, row_ptr, col_src);
    finalize_deg<<<(NN + 255) / 256, 256, 0, stream>>>(deg_out, row_ptr, isdo, isdi);

    // ---- conversions ----
    convert_x<<<NPAD * IN_F / 8 / 256, 256, 0, stream>>>(X, isdo, Xb);
    convert_wt<IN_F, HID><<<IN_F * HID / 256, 256, 0, stream>>>(W1, W1t);
    convert_wt<HID, HID><<<HID * HID / 256, 256, 0, stream>>>(W2, W2t);

    dim3 ggrid(NPAD / 128, 2);

    // ---- layer 1 ----
    gemm_bt<IN_F><<<ggrid, 256, 0, stream>>>(Xb, W1t, hA);
    gather_agg<0><<<NN / 4, 256, 0, stream>>>(hA, row_ptr, col_src, isdi, isdo, b1, hB);

    // ---- layer 2 ----
    gemm_bt<HID><<<ggrid, 256, 0, stream>>>(hB, W2t, h2pre);
    gather_agg<1><<<NN / 4, 256, 0, stream>>>(h2pre, row_ptr, col_src, isdi, isdo, b2, h2);

    // ---- head ----
    head_kernel<<<NN / 16, 256, 0, stream>>>(h2, W3, b3, out);
}

// Round 5
// 569.706 us; speedup vs baseline: 20.0935x; 1.0106x over previous
//
#include <hip/hip_runtime.h>
#include <stdint.h>

#define NN    100000
#define NE    1600000
#define IN_F  512
#define HID   256
#define OUTF  16
#define NPAD  100096   // 782 * 128
#define NBK   391      // ceil(NN/256) coarse buckets (dst>>8)
#define EPB   8192     // edges per block in bucket_scatter

typedef unsigned int u32;
typedef __bf16 bfrag  __attribute__((ext_vector_type(8)));
typedef float  f32x4  __attribute__((ext_vector_type(4)));
typedef short  s16x8  __attribute__((ext_vector_type(8)));

__device__ __forceinline__ u32 rotl32(u32 x, int r){ return (x<<r)|(x>>(32-r)); }

// JAX threefry2x32, key=(0,42), counts=(0,i). keep <=> top bit of (x0^x1)==0.
__device__ __forceinline__ bool drop_keep(u32 i){
    const u32 ks0 = 0u, ks1 = 42u, ks2 = 0x1BD11BDAu ^ 0u ^ 42u;
    u32 x0 = 0u + ks0;
    u32 x1 = i  + ks1;
#define TFR(r) { x0 += x1; x1 = rotl32(x1,(r)); x1 ^= x0; }
    TFR(13) TFR(15) TFR(26) TFR(6)   x0 += ks1; x1 += ks2 + 1u;
    TFR(17) TFR(29) TFR(16) TFR(24)  x0 += ks2; x1 += ks0 + 2u;
    TFR(13) TFR(15) TFR(26) TFR(6)   x0 += ks0; x1 += ks1 + 3u;
    TFR(17) TFR(29) TFR(16) TFR(24)  x0 += ks1; x1 += ks2 + 4u;
    TFR(13) TFR(15) TFR(26) TFR(6)   x0 += ks2; x1 += ks0 + 5u;
#undef TFR
    return ((x0 ^ x1) >> 31) == 0u;
}

__device__ __forceinline__ short f2b(float f){
    union { float f; u32 u; } v; v.f = f;
    u32 r = (v.u + 0x7FFFu + ((v.u >> 16) & 1u)) >> 16;   // RNE
    return (short)r;
}
__device__ __forceinline__ float blo(u32 u){ union{u32 u; float f;} v; v.u = u << 16;         return v.f; }
__device__ __forceinline__ float bhi(u32 u){ union{u32 u; float f;} v; v.u = u & 0xFFFF0000u; return v.f; }

__device__ __forceinline__ void gll16(const void* g, void* l){
    __builtin_amdgcn_global_load_lds((const __attribute__((address_space(1))) void*)g,
                                     (__attribute__((address_space(3))) void*)l, 16, 0, 0);
}

// ---------------- deg_out histogram ----------------

__global__ __launch_bounds__(256) void hist_kernel(const int4* __restrict__ src4,
                                                   int* deg_out){
    int i = blockIdx.x * blockDim.x + threadIdx.x;
    if (i < NE / 4) {
        int4 v = src4[i];
        atomicAdd(&deg_out[v.x], 1);
        atomicAdd(&deg_out[v.y], 1);
        atomicAdd(&deg_out[v.z], 1);
        atomicAdd(&deg_out[v.w], 1);
    }
}

__global__ __launch_bounds__(256) void finalize_deg(const int* __restrict__ deg_out,
                                                    const int* __restrict__ row_ptr,
                                                    float* isdo, float* isdi){
    int i = blockIdx.x * blockDim.x + threadIdx.x;
    if (i < NN) {
        isdo[i] = rsqrtf(fmaxf((float)deg_out[i], 1.0f));
        isdi[i] = rsqrtf(fmaxf((float)(row_ptr[i + 1] - row_ptr[i]), 1.0f));
    }
}

// ---------------- bucket-sort CSR build ----------------

__global__ __launch_bounds__(256) void bucket_hist(const int* __restrict__ dst,
                                                   int* __restrict__ bcnt){
    __shared__ int h[NBK];
    int t = threadIdx.x;
    for (int i = t; i < NBK; i += 256) h[i] = 0;
    __syncthreads();
    for (int i = blockIdx.x * 256 + t; i < NE; i += gridDim.x * 256)
        atomicAdd(&h[dst[i] >> 8], 1);
    __syncthreads();
    for (int i = t; i < NBK; i += 256)
        if (h[i]) atomicAdd(&bcnt[i], h[i]);
}

__global__ __launch_bounds__(512) void bucket_scan(const int* __restrict__ bcnt,
                                                   int* __restrict__ bbase,
                                                   int* __restrict__ bcur,
                                                   int* __restrict__ row_ptr){
    __shared__ int sh[512];
    int t = threadIdx.x;
    int v = (t < NBK) ? bcnt[t] : 0;
    sh[t] = v;
    __syncthreads();
    for (int off = 1; off < 512; off <<= 1) {
        int a = (t >= off) ? sh[t - off] : 0;
        __syncthreads();
        sh[t] += a;
        __syncthreads();
    }
    int excl = sh[t] - v;
    if (t < NBK) { bbase[t] = excl; bcur[t] = excl; }
    if (t == 0)  { bbase[NBK] = NE; row_ptr[NN] = NE; }
}

// Pass B: scatter packed (src<<8 | dst&255) into coarse-bucket regions
__global__ __launch_bounds__(256) void bucket_scatter(const int* __restrict__ src,
                                                      const int* __restrict__ dst,
                                                      int* bcur, u32* __restrict__ tmp){
    __shared__ int lh[NBK];
    __shared__ int lb[NBK];
    int t = threadIdx.x;
    for (int i = t; i < NBK; i += 256) lh[i] = 0;
    __syncthreads();
    const int e0 = blockIdx.x * EPB;
    for (int k = t; k < EPB; k += 256) {
        int e = e0 + k;
        if (e < NE) atomicAdd(&lh[dst[e] >> 8], 1);
    }
    __syncthreads();
    for (int i = t; i < NBK; i += 256) {
        int c = lh[i];
        if (c) lb[i] = atomicAdd(&bcur[i], c);
        lh[i] = 0;
    }
    __syncthreads();
    for (int k = t; k < EPB; k += 256) {
        int e = e0 + k;
        if (e < NE) {
            int d = dst[e], b = d >> 8;
            int r = atomicAdd(&lh[b], 1);
            tmp[lb[b] + r] = ((u32)src[e] << 8) | ((u32)d & 255u);
        }
    }
}

// Pass C: per-bucket counting sort by low 8 bits of dst
__global__ __launch_bounds__(256) void bucket_finalize(const u32* __restrict__ tmp,
                                                       const int* __restrict__ bbase,
                                                       int* __restrict__ row_ptr,
                                                       int* __restrict__ col_src){
    __shared__ int h[256];
    __shared__ int wtot[4];
    const int t = threadIdx.x;
    const int b = blockIdx.x;
    const int base = bbase[b];
    const int cnt  = bbase[b + 1] - base;
    h[t] = 0;
    __syncthreads();
    for (int k = t; k < cnt; k += 256)
        atomicAdd(&h[tmp[base + k] & 255u], 1);
    __syncthreads();
    int v = h[t];
    int lane = t & 63, w = t >> 6;
    int s = v;
    #pragma unroll
    for (int off = 1; off < 64; off <<= 1) {
        int u = __shfl_up(s, off);
        if (lane >= off) s += u;
    }
    if (lane == 63) wtot[w] = s;
    __syncthreads();
    int woff = 0;
    #pragma unroll
    for (int i = 0; i < 4; ++i) woff += (i < w) ? wtot[i] : 0;
    int excl = woff + s - v;
    int d = (b << 8) + t;
    if (d < NN) row_ptr[d] = base + excl;
    h[t] = excl;
    __syncthreads();
    for (int k = t; k < cnt; k += 256) {
        u32 p = tmp[base + k];
        int r = atomicAdd(&h[p & 255u], 1);
        col_src[base + r] = (int)(p >> 8);
    }
}

// ---------------- conversions ----------------

__global__ __launch_bounds__(256) void convert_x(const float* __restrict__ X,
                                                 const float* __restrict__ isdo,
                                                 short* __restrict__ Xb){
    int idx8 = blockIdx.x * 256 + threadIdx.x;
    int m = idx8 >> 6;
    s16x8 r;
    if (m < NN) {
        float s = isdo[m];
        const float4* p = (const float4*)(X + (size_t)idx8 * 8);
        float4 a = p[0], b = p[1];
        r[0] = f2b(a.x * s); r[1] = f2b(a.y * s); r[2] = f2b(a.z * s); r[3] = f2b(a.w * s);
        r[4] = f2b(b.x * s); r[5] = f2b(b.y * s); r[6] = f2b(b.z * s); r[7] = f2b(b.w * s);
    } else {
        r = (s16x8)0;
    }
    *(s16x8*)(Xb + (size_t)idx8 * 8) = r;
}

template<int Kd, int Nd>
__global__ __launch_bounds__(256) void convert_wt(const float* __restrict__ W,
                                                  short* __restrict__ WT){
    int i = blockIdx.x * 256 + threadIdx.x;
    if (i >= Kd * Nd) return;
    int n = i / Kd, k = i - n * Kd;
    WT[i] = f2b(W[(size_t)k * Nd + n]);
}

// ---------------- MFMA GEMM: C = A * BT^T ----------------
template<int K>
__global__ __launch_bounds__(256) void gemm_bt(const short* __restrict__ A,
                                               const short* __restrict__ BT,
                                               short* __restrict__ C){
    __shared__ short As[4096];
    __shared__ short Bs[4096];

    const int t = threadIdx.x;
    const int wave = t >> 6, lane = t & 63;
    const int bm = blockIdx.x * 128;
    const int bn = blockIdx.y * 128;

    const int ch0 = wave * 128 + lane;
    const int ch1 = ch0 + 64;
    const int kb0 = ch0 >> 7, r0 = ch0 & 127;
    const int kb1 = ch1 >> 7, r1 = ch1 & 127;
    const short* pa0 = A  + (size_t)(bm + r0) * K + kb0 * 8;
    const short* pa1 = A  + (size_t)(bm + r1) * K + kb1 * 8;
    const short* pb0 = BT + (size_t)(bn + r0) * K + kb0 * 8;
    const short* pb1 = BT + (size_t)(bn + r1) * K + kb1 * 8;
    short* lA0 = As + (size_t)(wave * 128) * 8;
    short* lA1 = As + (size_t)(wave * 128 + 64) * 8;
    short* lB0 = Bs + (size_t)(wave * 128) * 8;
    short* lB1 = Bs + (size_t)(wave * 128 + 64) * 8;

    const int wr = (wave >> 1) * 64, wc = (wave & 1) * 64;
    const short* fa = As + (size_t)((lane >> 4) * 128 + wr + (lane & 15)) * 8;
    const short* fb = Bs + (size_t)((lane >> 4) * 128 + wc + (lane & 15)) * 8;

    f32x4 acc[4][4];
    #pragma unroll
    for (int m = 0; m < 4; ++m)
        #pragma unroll
        for (int n = 0; n < 4; ++n) acc[m][n] = (f32x4)0.0f;

    for (int k0 = 0; k0 < K; k0 += 32) {
        gll16(pa0 + k0, lA0);
        gll16(pa1 + k0, lA1);
        gll16(pb0 + k0, lB0);
        gll16(pb1 + k0, lB1);
        __syncthreads();

        bfrag af[4], bfg[4];
        #pragma unroll
        for (int m = 0; m < 4; ++m) af[m]  = *(const bfrag*)(fa + m * 128);
        #pragma unroll
        for (int n = 0; n < 4; ++n) bfg[n] = *(const bfrag*)(fb + n * 128);
        #pragma unroll
        for (int m = 0; m < 4; ++m)
            #pragma unroll
            for (int n = 0; n < 4; ++n)
                acc[m][n] = __builtin_amdgcn_mfma_f32_16x16x32_bf16(af[m], bfg[n], acc[m][n], 0, 0, 0);
        __syncthreads();
    }

    const int crow0 = bm + wr + (lane >> 4) * 4;
    const int ccol0 = bn + wc + (lane & 15);
    #pragma unroll
    for (int m = 0; m < 4; ++m)
        #pragma unroll
        for (int n = 0; n < 4; ++n)
            #pragma unroll
            for (int r = 0; r < 4; ++r)
                C[(size_t)(crow0 + m * 16 + r) * HID + ccol0 + n * 16] = f2b(acc[m][n][r]);
}

// ---------------- gather aggregation: scalar edge fetch + saddr loads ----------------
template<int MODE>
__global__ __launch_bounds__(256) void gather_agg(const short* __restrict__ H,
                                                  const int* __restrict__ rp,
                                                  const int* __restrict__ cs,
                                                  const float* __restrict__ isdi,
                                                  const float* __restrict__ isdo,
                                                  const float* __restrict__ bias,
                                                  short* __restrict__ out){
    const int lane = threadIdx.x & 63;
    const int node = __builtin_amdgcn_readfirstlane((int)(blockIdx.x * 4) + (int)(threadIdx.x >> 6));
    const int e0  = rp[node];
    const int end = rp[node + 1];
    const u32 off = (u32)lane * 8u;
    const char* Hb = (const char*)H;

    float a0=0.f,a1=0.f,a2=0.f,a3=0.f;
    float c0=0.f,c1=0.f,c2=0.f,c3=0.f;

#define LDROW(su) (*(const uint2*)(Hb + ((((u32)(su)) << 9) | off)))
    int eb = e0;
    for (; eb + 8 <= end; eb += 8) {
        int s0 = cs[eb+0], s1 = cs[eb+1], s2 = cs[eb+2], s3 = cs[eb+3];
        int s4 = cs[eb+4], s5 = cs[eb+5], s6 = cs[eb+6], s7 = cs[eb+7];
        uint2 u0 = LDROW(s0), u1 = LDROW(s1), u2 = LDROW(s2), u3 = LDROW(s3);
        uint2 u4 = LDROW(s4), u5 = LDROW(s5), u6 = LDROW(s6), u7 = LDROW(s7);
        a0 += blo(u0.x); a1 += bhi(u0.x); a2 += blo(u0.y); a3 += bhi(u0.y);
        c0 += blo(u1.x); c1 += bhi(u1.x); c2 += blo(u1.y); c3 += bhi(u1.y);
        a0 += blo(u2.x); a1 += bhi(u2.x); a2 += blo(u2.y); a3 += bhi(u2.y);
        c0 += blo(u3.x); c1 += bhi(u3.x); c2 += blo(u3.y); c3 += bhi(u3.y);
        a0 += blo(u4.x); a1 += bhi(u4.x); a2 += blo(u4.y); a3 += bhi(u4.y);
        c0 += blo(u5.x); c1 += bhi(u5.x); c2 += blo(u5.y); c3 += bhi(u5.y);
        a0 += blo(u6.x); a1 += bhi(u6.x); a2 += blo(u6.y); a3 += bhi(u6.y);
        c0 += blo(u7.x); c1 += bhi(u7.x); c2 += blo(u7.y); c3 += bhi(u7.y);
    }
    for (; eb < end; ++eb) {
        int s0 = cs[eb];
        uint2 u0 = LDROW(s0);
        a0 += blo(u0.x); a1 += bhi(u0.x); a2 += blo(u0.y); a3 += bhi(u0.y);
    }
#undef LDROW
    a0 += c0; a1 += c1; a2 += c2; a3 += c3;

    float sd = isdi[node];
    float4 b = *(const float4*)((const char*)bias + off * 4);
    float h0 = a0 * sd + b.x;
    float h1 = a1 * sd + b.y;
    float h2 = a2 * sd + b.z;
    float h3 = a3 * sd + b.w;

    if (MODE == 0) {
        float so2 = 2.0f * isdo[node];
        u32 base = (u32)node * HID + (u32)lane * 4;
        h0 = drop_keep(base + 0) ? fmaxf(h0, 0.f) * so2 : 0.f;
        h1 = drop_keep(base + 1) ? fmaxf(h1, 0.f) * so2 : 0.f;
        h2 = drop_keep(base + 2) ? fmaxf(h2, 0.f) * so2 : 0.f;
        h3 = drop_keep(base + 3) ? fmaxf(h3, 0.f) * so2 : 0.f;
    }

    uint2 wv;
    wv.x = ((u32)(unsigned short)f2b(h1) << 16) | (u32)(unsigned short)f2b(h0);
    wv.y = ((u32)(unsigned short)f2b(h3) << 16) | (u32)(unsigned short)f2b(h2);
    *(uint2*)((char*)out + (size_t)node * 512 + off) = wv;
}

// ---------------- head ----------------
__global__ __launch_bounds__(256) void head_kernel(const short* __restrict__ H2,
                                                   const float* __restrict__ W3,
                                                   const float* __restrict__ b3,
                                                   float* __restrict__ out){
    __shared__ float W3s[HID * OUTF];
    __shared__ short rows[16][HID + 8];
    int t = threadIdx.x;
    for (int i = t; i < HID * OUTF; i += 256) W3s[i] = W3[i];
    const int n0 = blockIdx.x * 16;
    for (int c = t; c < 16 * 32; c += 256) {
        int r = c >> 5, cc = c & 31;
        *(s16x8*)(&rows[r][cc * 8]) = *(const s16x8*)(H2 + (size_t)(n0 + r) * HID + cc * 8);
    }
    __syncthreads();
    int nl = t >> 4, k = t & 15;
    float acc = 0.0f;
    #pragma unroll 4
    for (int j = 0; j < HID; ++j)
        acc += blo((u32)(unsigned short)rows[nl][j]) * W3s[j * OUTF + k];
    out[(size_t)(n0 + nl) * OUTF + k] = acc + b3[k];
}

extern "C" void kernel_launch(void* const* d_in, const int* in_sizes, int n_in,
                              void* d_out, int out_size, void* d_ws, size_t ws_size,
                              hipStream_t stream) {
    const float* X   = (const float*)d_in[0];
    const int*   src = (const int*)  d_in[1];
    const int*   dst = (const int*)  d_in[2];
    const float* W1  = (const float*)d_in[3];
    const float* b1  = (const float*)d_in[4];
    const float* W2  = (const float*)d_in[5];
    const float* b2  = (const float*)d_in[6];
    const float* W3  = (const float*)d_in[7];
    const float* b3  = (const float*)d_in[8];
    float* out = (float*)d_out;

    char* ws = (char*)d_ws;
    size_t o = 0;
    int*   deg_out = (int*)  (ws + o); o += (size_t)NN * 4;
    int*   bcnt    = (int*)  (ws + o); o += (size_t)NBK * 4;       // memset with deg_out
    float* isdo    = (float*)(ws + o); o += (size_t)NN * 4;
    float* isdi    = (float*)(ws + o); o += (size_t)NN * 4;
    int*   row_ptr = (int*)  (ws + o); o += (size_t)(NN + 1) * 4;
    int*   bbase   = (int*)  (ws + o); o += (size_t)(NBK + 1) * 4;
    int*   bcur    = (int*)  (ws + o); o += (size_t)NBK * 4;
    int*   col_src = (int*)  (ws + o); o += (size_t)NE * 4;
    o = (o + 255) & ~(size_t)255;
    short* W1t = (short*)(ws + o); o += (size_t)IN_F * HID * 2;
    short* W2t = (short*)(ws + o); o += (size_t)HID * HID * 2;
    o = (o + 255) & ~(size_t)255;
    short* Xb  = (short*)(ws + o); o += (size_t)NPAD * IN_F * 2;
    short* hA  = (short*)(ws + o); o += (size_t)NPAD * HID * 2;
    short* hB  = (short*)(ws + o); o += (size_t)NPAD * HID * 2;
    if (ws_size < o) return;
    short* h2pre = Xb;
    short* h2    = hA;
    u32*   tmp   = (u32*)hB;   // alias: tmp consumed before hB is first written

    const size_t zlen = (size_t)NN * 4 + (size_t)NBK * 4;  // deg_out + bcnt contiguous
    hipMemsetAsync(deg_out, 0, zlen, stream);

    // ---- CSR build (bucket sort) + degrees ----
    hist_kernel<<<(NE / 4 + 255) / 256, 256, 0, stream>>>((const int4*)src, deg_out);
    bucket_hist<<<256, 256, 0, stream>>>(dst, bcnt);
    bucket_scan<<<1, 512, 0, stream>>>(bcnt, bbase, bcur, row_ptr);
    bucket_scatter<<<(NE + EPB - 1) / EPB, 256, 0, stream>>>(src, dst, bcur, tmp);
    bucket_finalize<<<NBK, 256, 0, stream>>>(tmp, bbase, row_ptr, col_src);
    finalize_deg<<<(NN + 255) / 256, 256, 0, stream>>>(deg_out, row_ptr, isdo, isdi);

    // ---- conversions ----
    convert_x<<<NPAD * IN_F / 8 / 256, 256, 0, stream>>>(X, isdo, Xb);
    convert_wt<IN_F, HID><<<IN_F * HID / 256, 256, 0, stream>>>(W1, W1t);
    convert_wt<HID, HID><<<HID * HID / 256, 256, 0, stream>>>(W2, W2t);

    dim3 ggrid(NPAD / 128, 2);

    // ---- layer 1 ----
    gemm_bt<IN_F><<<ggrid, 256, 0, stream>>>(Xb, W1t, hA);
    gather_agg<0><<<NN / 4, 256, 0, stream>>>(hA, row_ptr, col_src, isdi, isdo, b1, hB);

    // ---- layer 2 ----
    gemm_bt<HID><<<ggrid, 256, 0, stream>>>(hB, W2t, h2pre);
    gather_agg<1><<<NN / 4, 256, 0, stream>>>(h2pre, row_ptr, col_src, isdi, isdo, b2, h2);

    // ---- head ----
    head_kernel<<<NN / 16, 256, 0, stream>>>(h2, W3, b3, out);
}

// Round 6
// 535.654 us; speedup vs baseline: 21.3709x; 1.0636x over previous
//
#include <hip/hip_runtime.h>
#include <stdint.h>

#define NN    100000
#define NE    1600000
#define IN_F  512
#define HID   256
#define OUTF  16
#define NPAD  100096   // 782 * 128
#define NBK   391      // ceil(NN/256) coarse buckets (dst>>8)
#define EPB   8192     // edges per block in bucket_scatter

typedef unsigned int u32;
typedef __bf16 bfrag  __attribute__((ext_vector_type(8)));
typedef float  f32x4  __attribute__((ext_vector_type(4)));
typedef short  s16x8  __attribute__((ext_vector_type(8)));

__device__ __forceinline__ u32 rotl32(u32 x, int r){ return (x<<r)|(x>>(32-r)); }

// JAX threefry2x32, key=(0,42), counts=(0,i). keep <=> top bit of (x0^x1)==0.
__device__ __forceinline__ bool drop_keep(u32 i){
    const u32 ks0 = 0u, ks1 = 42u, ks2 = 0x1BD11BDAu ^ 0u ^ 42u;
    u32 x0 = 0u + ks0;
    u32 x1 = i  + ks1;
#define TFR(r) { x0 += x1; x1 = rotl32(x1,(r)); x1 ^= x0; }
    TFR(13) TFR(15) TFR(26) TFR(6)   x0 += ks1; x1 += ks2 + 1u;
    TFR(17) TFR(29) TFR(16) TFR(24)  x0 += ks2; x1 += ks0 + 2u;
    TFR(13) TFR(15) TFR(26) TFR(6)   x0 += ks0; x1 += ks1 + 3u;
    TFR(17) TFR(29) TFR(16) TFR(24)  x0 += ks1; x1 += ks2 + 4u;
    TFR(13) TFR(15) TFR(26) TFR(6)   x0 += ks2; x1 += ks0 + 5u;
#undef TFR
    return ((x0 ^ x1) >> 31) == 0u;
}

__device__ __forceinline__ short f2b(float f){
    union { float f; u32 u; } v; v.f = f;
    u32 r = (v.u + 0x7FFFu + ((v.u >> 16) & 1u)) >> 16;   // RNE
    return (short)r;
}
__device__ __forceinline__ float blo(u32 u){ union{u32 u; float f;} v; v.u = u << 16;         return v.f; }
__device__ __forceinline__ float bhi(u32 u){ union{u32 u; float f;} v; v.u = u & 0xFFFF0000u; return v.f; }

__device__ __forceinline__ u32 cvt_pk_bf16(float lo, float hi){
    u32 r;
    asm("v_cvt_pk_bf16_f32 %0, %1, %2" : "=v"(r) : "v"(lo), "v"(hi));
    return r;
}

__device__ __forceinline__ void gll16(const void* g, void* l){
    __builtin_amdgcn_global_load_lds((const __attribute__((address_space(1))) void*)g,
                                     (__attribute__((address_space(3))) void*)l, 16, 0, 0);
}

// ---------------- combined histogram: deg_out (global atomics) + coarse dst buckets ----------------

__global__ __launch_bounds__(256) void build_hist(const int4* __restrict__ src4,
                                                  const int4* __restrict__ dst4,
                                                  int* deg_out, int* __restrict__ bcnt){
    __shared__ int h[NBK];
    int t = threadIdx.x;
    for (int i = t; i < NBK; i += 256) h[i] = 0;
    __syncthreads();
    for (int i = blockIdx.x * 256 + t; i < NE / 4; i += gridDim.x * 256) {
        int4 s = src4[i];
        int4 d = dst4[i];
        atomicAdd(&deg_out[s.x], 1);
        atomicAdd(&deg_out[s.y], 1);
        atomicAdd(&deg_out[s.z], 1);
        atomicAdd(&deg_out[s.w], 1);
        atomicAdd(&h[d.x >> 8], 1);
        atomicAdd(&h[d.y >> 8], 1);
        atomicAdd(&h[d.z >> 8], 1);
        atomicAdd(&h[d.w >> 8], 1);
    }
    __syncthreads();
    for (int i = t; i < NBK; i += 256)
        if (h[i]) atomicAdd(&bcnt[i], h[i]);
}

__global__ __launch_bounds__(256) void finalize_deg(const int* __restrict__ deg_out,
                                                    const int* __restrict__ row_ptr,
                                                    float* isdo, float* isdi){
    int i = blockIdx.x * blockDim.x + threadIdx.x;
    if (i < NN) {
        isdo[i] = rsqrtf(fmaxf((float)deg_out[i], 1.0f));
        isdi[i] = rsqrtf(fmaxf((float)(row_ptr[i + 1] - row_ptr[i]), 1.0f));
    }
}

__global__ __launch_bounds__(512) void bucket_scan(const int* __restrict__ bcnt,
                                                   int* __restrict__ bbase,
                                                   int* __restrict__ bcur,
                                                   int* __restrict__ row_ptr){
    __shared__ int sh[512];
    int t = threadIdx.x;
    int v = (t < NBK) ? bcnt[t] : 0;
    sh[t] = v;
    __syncthreads();
    for (int off = 1; off < 512; off <<= 1) {
        int a = (t >= off) ? sh[t - off] : 0;
        __syncthreads();
        sh[t] += a;
        __syncthreads();
    }
    int excl = sh[t] - v;
    if (t < NBK) { bbase[t] = excl; bcur[t] = excl; }
    if (t == 0)  { bbase[NBK] = NE; row_ptr[NN] = NE; }
}

// Pass B: scatter packed (src<<8 | dst&255) into coarse-bucket regions
__global__ __launch_bounds__(256) void bucket_scatter(const int* __restrict__ src,
                                                      const int* __restrict__ dst,
                                                      int* bcur, u32* __restrict__ tmp){
    __shared__ int lh[NBK];
    __shared__ int lb[NBK];
    int t = threadIdx.x;
    for (int i = t; i < NBK; i += 256) lh[i] = 0;
    __syncthreads();
    const int e0 = blockIdx.x * EPB;
    for (int k = t * 4; k < EPB; k += 1024) {
        int e = e0 + k;
        if (e < NE) {   // e multiple of 4, NE multiple of 4 -> all 4 valid
            int4 d = *(const int4*)(dst + e);
            atomicAdd(&lh[d.x >> 8], 1);
            atomicAdd(&lh[d.y >> 8], 1);
            atomicAdd(&lh[d.z >> 8], 1);
            atomicAdd(&lh[d.w >> 8], 1);
        }
    }
    __syncthreads();
    for (int i = t; i < NBK; i += 256) {
        int c = lh[i];
        if (c) lb[i] = atomicAdd(&bcur[i], c);
        lh[i] = 0;
    }
    __syncthreads();
    for (int k = t * 4; k < EPB; k += 1024) {
        int e = e0 + k;
        if (e < NE) {
            int4 d = *(const int4*)(dst + e);
            int4 s = *(const int4*)(src + e);
            int b0 = d.x >> 8, b1 = d.y >> 8, b2 = d.z >> 8, b3 = d.w >> 8;
            int r0 = atomicAdd(&lh[b0], 1);
            tmp[lb[b0] + r0] = ((u32)s.x << 8) | ((u32)d.x & 255u);
            int r1 = atomicAdd(&lh[b1], 1);
            tmp[lb[b1] + r1] = ((u32)s.y << 8) | ((u32)d.y & 255u);
            int r2 = atomicAdd(&lh[b2], 1);
            tmp[lb[b2] + r2] = ((u32)s.z << 8) | ((u32)d.z & 255u);
            int r3 = atomicAdd(&lh[b3], 1);
            tmp[lb[b3] + r3] = ((u32)s.w << 8) | ((u32)d.w & 255u);
        }
    }
}

// Pass C: per-bucket counting sort by low 8 bits of dst
__global__ __launch_bounds__(256) void bucket_finalize(const u32* __restrict__ tmp,
                                                       const int* __restrict__ bbase,
                                                       int* __restrict__ row_ptr,
                                                       int* __restrict__ col_src){
    __shared__ int h[256];
    __shared__ int wtot[4];
    const int t = threadIdx.x;
    const int b = blockIdx.x;
    const int base = bbase[b];
    const int cnt  = bbase[b + 1] - base;
    h[t] = 0;
    __syncthreads();
    for (int k = t; k < cnt; k += 256)
        atomicAdd(&h[tmp[base + k] & 255u], 1);
    __syncthreads();
    int v = h[t];
    int lane = t & 63, w = t >> 6;
    int s = v;
    #pragma unroll
    for (int off = 1; off < 64; off <<= 1) {
        int u = __shfl_up(s, off);
        if (lane >= off) s += u;
    }
    if (lane == 63) wtot[w] = s;
    __syncthreads();
    int woff = 0;
    #pragma unroll
    for (int i = 0; i < 4; ++i) woff += (i < w) ? wtot[i] : 0;
    int excl = woff + s - v;
    int d = (b << 8) + t;
    if (d < NN) row_ptr[d] = base + excl;
    h[t] = excl;
    __syncthreads();
    for (int k = t; k < cnt; k += 256) {
        u32 p = tmp[base + k];
        int r = atomicAdd(&h[p & 255u], 1);
        col_src[base + r] = (int)(p >> 8);
    }
}

// ---------------- weight transpose+convert ----------------

template<int Kd, int Nd>
__global__ __launch_bounds__(256) void convert_wt(const float* __restrict__ W,
                                                  short* __restrict__ WT){
    int i = blockIdx.x * 256 + threadIdx.x;
    if (i >= Kd * Nd) return;
    int n = i / Kd, k = i - n * Kd;
    WT[i] = f2b(W[(size_t)k * Nd + n]);
}

// ---------------- GEMM1: C = (X fp32) * W1t^T, isdo row-scale in epilogue ----------------
// A staged in registers with cvt_pk_bf16; B via global_load_lds. LDS layout [kb][row][8].
__global__ __launch_bounds__(256) void gemm_x(const float* __restrict__ X,
                                              const short* __restrict__ BT,
                                              const float* __restrict__ isdo,
                                              short* __restrict__ C){
    __shared__ short As[4096];
    __shared__ short Bs[4096];

    const int t = threadIdx.x;
    const int wave = t >> 6, lane = t & 63;
    const int bm = blockIdx.x * 128;
    const int bn = blockIdx.y * 128;

    // A staging: thread covers row = t>>1, k-halfstep kh = t&1 (16 floats)
    const int arow = t >> 1;
    const int kh   = t & 1;
    const bool rv  = (bm + arow) < NN;
    const float* px = X + (size_t)(bm + arow) * IN_F + kh * 16;
    short* wA = As + ((kh * 2) * 128 + arow) * 8;   // chunk (kb=2kh,row); second at +1024 shorts

    // B staging (async)
    const int ch0 = wave * 128 + lane;
    const int ch1 = ch0 + 64;
    const int kb0 = ch0 >> 7, r0 = ch0 & 127;
    const int kb1 = ch1 >> 7, r1 = ch1 & 127;
    const short* pb0 = BT + (size_t)(bn + r0) * IN_F + kb0 * 8;
    const short* pb1 = BT + (size_t)(bn + r1) * IN_F + kb1 * 8;
    short* lB0 = Bs + (size_t)(wave * 128) * 8;
    short* lB1 = Bs + (size_t)(wave * 128 + 64) * 8;

    const int wr = (wave >> 1) * 64, wc = (wave & 1) * 64;
    const short* fa = As + (size_t)((lane >> 4) * 128 + wr + (lane & 15)) * 8;
    const short* fb = Bs + (size_t)((lane >> 4) * 128 + wc + (lane & 15)) * 8;

    f32x4 acc[4][4];
    #pragma unroll
    for (int m = 0; m < 4; ++m)
        #pragma unroll
        for (int n = 0; n < 4; ++n) acc[m][n] = (f32x4)0.0f;

    for (int k0 = 0; k0 < IN_F; k0 += 32) {
        gll16(pb0 + k0, lB0);
        gll16(pb1 + k0, lB1);

        float4 x0, x1, x2, x3;
        if (rv) {
            const float4* p4 = (const float4*)(px + k0);
            x0 = p4[0]; x1 = p4[1]; x2 = p4[2]; x3 = p4[3];
        } else {
            x0 = x1 = x2 = x3 = make_float4(0.f, 0.f, 0.f, 0.f);
        }
        u32 q0 = cvt_pk_bf16(x0.x, x0.y), q1 = cvt_pk_bf16(x0.z, x0.w);
        u32 q2 = cvt_pk_bf16(x1.x, x1.y), q3 = cvt_pk_bf16(x1.z, x1.w);
        u32 q4 = cvt_pk_bf16(x2.x, x2.y), q5 = cvt_pk_bf16(x2.z, x2.w);
        u32 q6 = cvt_pk_bf16(x3.x, x3.y), q7 = cvt_pk_bf16(x3.z, x3.w);
        *(uint4*)(wA)        = make_uint4(q0, q1, q2, q3);
        *(uint4*)(wA + 1024) = make_uint4(q4, q5, q6, q7);
        __syncthreads();

        bfrag af[4], bfg[4];
        #pragma unroll
        for (int m = 0; m < 4; ++m) af[m]  = *(const bfrag*)(fa + m * 128);
        #pragma unroll
        for (int n = 0; n < 4; ++n) bfg[n] = *(const bfrag*)(fb + n * 128);
        #pragma unroll
        for (int m = 0; m < 4; ++m)
            #pragma unroll
            for (int n = 0; n < 4; ++n)
                acc[m][n] = __builtin_amdgcn_mfma_f32_16x16x32_bf16(af[m], bfg[n], acc[m][n], 0, 0, 0);
        __syncthreads();
    }

    const int crow0 = bm + wr + (lane >> 4) * 4;
    const int ccol0 = bn + wc + (lane & 15);
    #pragma unroll
    for (int m = 0; m < 4; ++m)
        #pragma unroll
        for (int r = 0; r < 4; ++r) {
            int row = crow0 + m * 16 + r;
            float sc = (row < NN) ? isdo[row] : 0.0f;
            #pragma unroll
            for (int n = 0; n < 4; ++n)
                C[(size_t)row * HID + ccol0 + n * 16] = f2b(acc[m][n][r] * sc);
        }
}

// ---------------- GEMM2: C = A * BT^T (all bf16, async staging) ----------------
template<int K>
__global__ __launch_bounds__(256) void gemm_bt(const short* __restrict__ A,
                                               const short* __restrict__ BT,
                                               short* __restrict__ C){
    __shared__ short As[4096];
    __shared__ short Bs[4096];

    const int t = threadIdx.x;
    const int wave = t >> 6, lane = t & 63;
    const int bm = blockIdx.x * 128;
    const int bn = blockIdx.y * 128;

    const int ch0 = wave * 128 + lane;
    const int ch1 = ch0 + 64;
    const int kb0 = ch0 >> 7, r0 = ch0 & 127;
    const int kb1 = ch1 >> 7, r1 = ch1 & 127;
    const short* pa0 = A  + (size_t)(bm + r0) * K + kb0 * 8;
    const short* pa1 = A  + (size_t)(bm + r1) * K + kb1 * 8;
    const short* pb0 = BT + (size_t)(bn + r0) * K + kb0 * 8;
    const short* pb1 = BT + (size_t)(bn + r1) * K + kb1 * 8;
    short* lA0 = As + (size_t)(wave * 128) * 8;
    short* lA1 = As + (size_t)(wave * 128 + 64) * 8;
    short* lB0 = Bs + (size_t)(wave * 128) * 8;
    short* lB1 = Bs + (size_t)(wave * 128 + 64) * 8;

    const int wr = (wave >> 1) * 64, wc = (wave & 1) * 64;
    const short* fa = As + (size_t)((lane >> 4) * 128 + wr + (lane & 15)) * 8;
    const short* fb = Bs + (size_t)((lane >> 4) * 128 + wc + (lane & 15)) * 8;

    f32x4 acc[4][4];
    #pragma unroll
    for (int m = 0; m < 4; ++m)
        #pragma unroll
        for (int n = 0; n < 4; ++n) acc[m][n] = (f32x4)0.0f;

    for (int k0 = 0; k0 < K; k0 += 32) {
        gll16(pa0 + k0, lA0);
        gll16(pa1 + k0, lA1);
        gll16(pb0 + k0, lB0);
        gll16(pb1 + k0, lB1);
        __syncthreads();

        bfrag af[4], bfg[4];
        #pragma unroll
        for (int m = 0; m < 4; ++m) af[m]  = *(const bfrag*)(fa + m * 128);
        #pragma unroll
        for (int n = 0; n < 4; ++n) bfg[n] = *(const bfrag*)(fb + n * 128);
        #pragma unroll
        for (int m = 0; m < 4; ++m)
            #pragma unroll
            for (int n = 0; n < 4; ++n)
                acc[m][n] = __builtin_amdgcn_mfma_f32_16x16x32_bf16(af[m], bfg[n], acc[m][n], 0, 0, 0);
        __syncthreads();
    }

    const int crow0 = bm + wr + (lane >> 4) * 4;
    const int ccol0 = bn + wc + (lane & 15);
    #pragma unroll
    for (int m = 0; m < 4; ++m)
        #pragma unroll
        for (int n = 0; n < 4; ++n)
            #pragma unroll
            for (int r = 0; r < 4; ++r)
                C[(size_t)(crow0 + m * 16 + r) * HID + ccol0 + n * 16] = f2b(acc[m][n][r]);
}

// ---------------- gather aggregation: 2 edges/wave-iter, dwordx4 per lane ----------------
// lanes 0-31 handle edge e (16B each at col sub*8), lanes 32-63 edge e+1.
template<int MODE>
__global__ __launch_bounds__(256) void gather_agg(const short* __restrict__ H,
                                                  const int* __restrict__ rp,
                                                  const int* __restrict__ cs,
                                                  const float* __restrict__ isdi,
                                                  const float* __restrict__ isdo,
                                                  const float* __restrict__ bias,
                                                  short* __restrict__ out){
    const int lane = threadIdx.x & 63;
    const int node = __builtin_amdgcn_readfirstlane((int)(blockIdx.x * 4) + (int)(threadIdx.x >> 6));
    const int e0  = rp[node];
    const int end = rp[node + 1];
    const int sub = lane & 31, half = lane >> 5;
    const u32 off16 = (u32)sub * 16u;
    const char* Hb = (const char*)H;

    float a[8] = {0,0,0,0,0,0,0,0};
    float b[8] = {0,0,0,0,0,0,0,0};

#define LD4(s) (*(const uint4*)(Hb + ((((u32)(s)) << 9) | off16)))
#define ACC(A, u) { A[0]+=blo(u.x); A[1]+=bhi(u.x); A[2]+=blo(u.y); A[3]+=bhi(u.y); \
                    A[4]+=blo(u.z); A[5]+=bhi(u.z); A[6]+=blo(u.w); A[7]+=bhi(u.w); }

    int eb = e0;
    for (; eb + 8 <= end; eb += 8) {
        int t0 = cs[eb+0], t1 = cs[eb+1], t2 = cs[eb+2], t3 = cs[eb+3];
        int t4 = cs[eb+4], t5 = cs[eb+5], t6 = cs[eb+6], t7 = cs[eb+7];
        int s0 = half ? t1 : t0;
        int s1 = half ? t3 : t2;
        int s2 = half ? t5 : t4;
        int s3 = half ? t7 : t6;
        uint4 u0 = LD4(s0), u1 = LD4(s1), u2 = LD4(s2), u3 = LD4(s3);
        ACC(a, u0); ACC(b, u1); ACC(a, u2); ACC(b, u3);
    }
    for (; eb + 2 <= end; eb += 2) {
        int t0 = cs[eb], t1 = cs[eb+1];
        int s = half ? t1 : t0;
        uint4 u = LD4(s);
        ACC(a, u);
    }
    if (eb < end) {
        int s = cs[eb];
        uint4 u = LD4(s);
        if (half == 0) { ACC(a, u); }
    }
#undef ACC
#undef LD4
    #pragma unroll
    for (int j = 0; j < 8; ++j) a[j] += b[j];

    // redistribute: col c = lane*4+j lives in lanes (c>>3) and (c>>3)+32, reg c&7
    const int srcl = lane >> 1;
    const bool oddq = (lane & 1) != 0;
    float v[4];
    #pragma unroll
    for (int j = 0; j < 4; ++j) {
        float p0 = __shfl(a[j],     srcl);
        float p1 = __shfl(a[j + 4], srcl);
        float q0 = __shfl(a[j],     srcl + 32);
        float q1 = __shfl(a[j + 4], srcl + 32);
        v[j] = oddq ? (p1 + q1) : (p0 + q0);
    }

    float sd = isdi[node];
    float4 bb = *(const float4*)(bias + lane * 4);
    float h0 = v[0] * sd + bb.x;
    float h1 = v[1] * sd + bb.y;
    float h2 = v[2] * sd + bb.z;
    float h3 = v[3] * sd + bb.w;

    if (MODE == 0) {
        float so2 = 2.0f * isdo[node];
        u32 base = (u32)node * HID + (u32)lane * 4;
        h0 = drop_keep(base + 0) ? fmaxf(h0, 0.f) * so2 : 0.f;
        h1 = drop_keep(base + 1) ? fmaxf(h1, 0.f) * so2 : 0.f;
        h2 = drop_keep(base + 2) ? fmaxf(h2, 0.f) * so2 : 0.f;
        h3 = drop_keep(base + 3) ? fmaxf(h3, 0.f) * so2 : 0.f;
    }

    uint2 wv;
    wv.x = ((u32)(unsigned short)f2b(h1) << 16) | (u32)(unsigned short)f2b(h0);
    wv.y = ((u32)(unsigned short)f2b(h3) << 16) | (u32)(unsigned short)f2b(h2);
    *(uint2*)((char*)out + (size_t)node * 512 + (u32)lane * 8u) = wv;
}

// ---------------- head ----------------
__global__ __launch_bounds__(256) void head_kernel(const short* __restrict__ H2,
                                                   const float* __restrict__ W3,
                                                   const float* __restrict__ b3,
                                                   float* __restrict__ out){
    __shared__ float W3s[HID * OUTF];
    __shared__ short rows[16][HID + 8];
    int t = threadIdx.x;
    for (int i = t; i < HID * OUTF; i += 256) W3s[i] = W3[i];
    const int n0 = blockIdx.x * 16;
    for (int c = t; c < 16 * 32; c += 256) {
        int r = c >> 5, cc = c & 31;
        *(s16x8*)(&rows[r][cc * 8]) = *(const s16x8*)(H2 + (size_t)(n0 + r) * HID + cc * 8);
    }
    __syncthreads();
    int nl = t >> 4, k = t & 15;
    float acc = 0.0f;
    #pragma unroll 4
    for (int j = 0; j < HID; ++j)
        acc += blo((u32)(unsigned short)rows[nl][j]) * W3s[j * OUTF + k];
    out[(size_t)(n0 + nl) * OUTF + k] = acc + b3[k];
}

extern "C" void kernel_launch(void* const* d_in, const int* in_sizes, int n_in,
                              void* d_out, int out_size, void* d_ws, size_t ws_size,
                              hipStream_t stream) {
    const float* X   = (const float*)d_in[0];
    const int*   src = (const int*)  d_in[1];
    const int*   dst = (const int*)  d_in[2];
    const float* W1  = (const float*)d_in[3];
    const float* b1  = (const float*)d_in[4];
    const float* W2  = (const float*)d_in[5];
    const float* b2  = (const float*)d_in[6];
    const float* W3  = (const float*)d_in[7];
    const float* b3  = (const float*)d_in[8];
    float* out = (float*)d_out;

    char* ws = (char*)d_ws;
    size_t o = 0;
    int*   deg_out = (int*)  (ws + o); o += (size_t)NN * 4;
    int*   bcnt    = (int*)  (ws + o); o += (size_t)NBK * 4;       // memset with deg_out
    float* isdo    = (float*)(ws + o); o += (size_t)NN * 4;
    float* isdi    = (float*)(ws + o); o += (size_t)NN * 4;
    int*   row_ptr = (int*)  (ws + o); o += (size_t)(NN + 1) * 4;
    int*   bbase   = (int*)  (ws + o); o += (size_t)(NBK + 1) * 4;
    int*   bcur    = (int*)  (ws + o); o += (size_t)NBK * 4;
    int*   col_src = (int*)  (ws + o); o += (size_t)NE * 4;
    o = (o + 255) & ~(size_t)255;
    short* W1t = (short*)(ws + o); o += (size_t)IN_F * HID * 2;
    short* W2t = (short*)(ws + o); o += (size_t)HID * HID * 2;
    o = (o + 255) & ~(size_t)255;
    short* hA    = (short*)(ws + o); o += (size_t)NPAD * HID * 2;   // h0, later h2
    short* hB    = (short*)(ws + o); o += (size_t)NPAD * HID * 2;   // h1*isdo (tmp alias)
    short* h2pre = (short*)(ws + o); o += (size_t)NPAD * HID * 2;
    if (ws_size < o) return;
    short* h2  = hA;
    u32*   tmp = (u32*)hB;   // alias: tmp consumed (bucket passes) before hB first written

    const size_t zlen = (size_t)NN * 4 + (size_t)NBK * 4;  // deg_out + bcnt contiguous
    hipMemsetAsync(deg_out, 0, zlen, stream);

    // ---- CSR build (bucket sort) + degrees ----
    build_hist<<<256, 256, 0, stream>>>((const int4*)src, (const int4*)dst, deg_out, bcnt);
    bucket_scan<<<1, 512, 0, stream>>>(bcnt, bbase, bcur, row_ptr);
    bucket_scatter<<<(NE + EPB - 1) / EPB, 256, 0, stream>>>(src, dst, bcur, tmp);
    bucket_finalize<<<NBK, 256, 0, stream>>>(tmp, bbase, row_ptr, col_src);
    finalize_deg<<<(NN + 255) / 256, 256, 0, stream>>>(deg_out, row_ptr, isdo, isdi);

    // ---- weight conversions ----
    convert_wt<IN_F, HID><<<IN_F * HID / 256, 256, 0, stream>>>(W1, W1t);
    convert_wt<HID, HID><<<HID * HID / 256, 256, 0, stream>>>(W2, W2t);

    dim3 ggrid(NPAD / 128, 2);

    // ---- layer 1 ----
    gemm_x<<<ggrid, 256, 0, stream>>>(X, W1t, isdo, hA);
    gather_agg<0><<<NN / 4, 256, 0, stream>>>(hA, row_ptr, col_src, isdi, isdo, b1, hB);

    // ---- layer 2 ----
    gemm_bt<HID><<<ggrid, 256, 0, stream>>>(hB, W2t, h2pre);
    gather_agg<1><<<NN / 4, 256, 0, stream>>>(h2pre, row_ptr, col_src, isdi, isdo, b2, h2);

    // ---- head ----
    head_kernel<<<NN / 16, 256, 0, stream>>>(h2, W3, b3, out);
}